// Round 20
// baseline (269.543 us; speedup 1.0000x reference)
//
#include <hip/hip_runtime.h>
#include <hip/hip_bf16.h>

// Transformer block fwd: B=2, T=2048, C=1024, H=16, D=64.
// out = concat(x_out fp32 [2,2048,1024], k fp32 [2,16,2048,64], v fp32 [2,16,2048,64])

#define T_SEQ 2048
#define C_DIM 1024
#define HEADS 16
#define HD    64

typedef __attribute__((ext_vector_type(8))) short s16x8;   // 8 x bf16 (4 VGPR) — MFMA A/B frag
typedef __attribute__((ext_vector_type(4))) short s16x4;
typedef __attribute__((ext_vector_type(4))) float f32x4;   // MFMA C/D frag

__device__ __forceinline__ short f2bf(float f) {
    union { __hip_bfloat16 h; short s; } u;
    u.h = __float2bfloat16(f);
    return u.s;
}
__device__ __forceinline__ float bf2f(short s) {
    union { float f; unsigned u; } u;
    u.u = ((unsigned)(unsigned short)s) << 16;
    return u.f;
}

// async global->LDS, 16B per lane. LDS dest = wave-uniform base + lane*16 (linear).
__device__ __forceinline__ void gload16(const void* g, void* l) {
    __builtin_amdgcn_global_load_lds(
        (const __attribute__((address_space(1))) void*)g,
        (__attribute__((address_space(3))) void*)l, 16, 0, 0);
}
#define VMCNT0 asm volatile("s_waitcnt vmcnt(0)" ::: "memory")
#define PRIO1  __builtin_amdgcn_s_setprio(1)
#define PRIO0  __builtin_amdgcn_s_setprio(0)

// ---------------- fused prep: 5 weight transposes (fp32 -> bf16, [K][N] -> [N][K]) + LN1 ----
__global__ __launch_bounds__(256) void prep_kernel(
    const float* __restrict__ wq, const float* __restrict__ wk, const float* __restrict__ wv,
    const float* __restrict__ wfc, const float* __restrict__ wpr,
    short* __restrict__ wqkvt, short* __restrict__ wfct, short* __restrict__ wprt,
    const float* __restrict__ x, const float* __restrict__ ln1w, const float* __restrict__ ln1b,
    short* __restrict__ hb) {
    int b = blockIdx.x, tid = threadIdx.x;
    if (b < 11264) {
        const float* W; short* Wt; int K, N, n0, k0;
        if (b < 3072) {
            int which = b >> 10, sub = b & 1023;
            W = (which == 0) ? wq : ((which == 1) ? wk : wv);
            Wt = wqkvt + which * 1024 * 1024;
            K = 1024; N = 1024;
            n0 = (sub & 31) * 32; k0 = (sub >> 5) * 32;
        } else if (b < 7168) {
            int sub = b - 3072;
            W = wfc; Wt = wfct; K = 1024; N = 4096;
            n0 = (sub & 127) * 32; k0 = (sub >> 7) * 32;
        } else {
            int sub = b - 7168;
            W = wpr; Wt = wprt; K = 4096; N = 1024;
            n0 = (sub & 31) * 32; k0 = (sub >> 5) * 32;
        }
        __shared__ float t[32][33];
        int ty = tid >> 3, tx = tid & 7;
        float4 v = *(const float4*)&W[(size_t)(k0 + ty) * N + n0 + tx * 4];
        t[ty][tx * 4 + 0] = v.x; t[ty][tx * 4 + 1] = v.y;
        t[ty][tx * 4 + 2] = v.z; t[ty][tx * 4 + 3] = v.w;
        __syncthreads();
        int r = tid >> 3, c = tid & 7;
        s16x4 o;
#pragma unroll
        for (int j = 0; j < 4; j++) o[j] = f2bf(t[c * 4 + j][r]);
        *(s16x4*)&Wt[(size_t)(n0 + r) * K + k0 + c * 4] = o;
    } else {
        int row = b - 11264;
        float4 v = ((const float4*)(x + (size_t)row * C_DIM))[tid];
        float s  = v.x + v.y + v.z + v.w;
        float sq = v.x * v.x + v.y * v.y + v.z * v.z + v.w * v.w;
#pragma unroll
        for (int off = 32; off > 0; off >>= 1) {
            s  += __shfl_down(s, off, 64);
            sq += __shfl_down(sq, off, 64);
        }
        __shared__ float rs[4], rq[4];
        int wv2 = tid >> 6, ln = tid & 63;
        if (ln == 0) { rs[wv2] = s; rq[wv2] = sq; }
        __syncthreads();
        s = rs[0] + rs[1] + rs[2] + rs[3];
        sq = rq[0] + rq[1] + rq[2] + rq[3];
        float mean = s * (1.f / C_DIM);
        float rstd = rsqrtf(sq * (1.f / C_DIM) - mean * mean + 1e-5f);
        float4 wv4 = ((const float4*)ln1w)[tid];
        float4 bv4 = ((const float4*)ln1b)[tid];
        s16x4 o;
        o[0] = f2bf((v.x - mean) * rstd * wv4.x + bv4.x);
        o[1] = f2bf((v.y - mean) * rstd * wv4.y + bv4.y);
        o[2] = f2bf((v.z - mean) * rstd * wv4.z + bv4.z);
        o[3] = f2bf((v.w - mean) * rstd * wv4.w + bv4.w);
        *(s16x4*)(hb + (size_t)row * C_DIM + tid * 4) = o;
    }
}

// ---- residual + LN2 + PROJ-output init: xout = x+y+b_proj (fp32), h2 = LN(x+y) bf16 ----
__global__ __launch_bounds__(256) void resln_kernel(
    const float* __restrict__ x, const float* __restrict__ y,
    const float* __restrict__ w, const float* __restrict__ b,
    const float* __restrict__ bproj,
    short* __restrict__ out, float* __restrict__ xout) {
    int row = blockIdx.x, tid = threadIdx.x;
    float4 vx = ((const float4*)(x + row * C_DIM))[tid];
    float4 vy = ((const float4*)(y + row * C_DIM))[tid];
    float4 v;
    v.x = vx.x + vy.x; v.y = vx.y + vy.y; v.z = vx.z + vy.z; v.w = vx.w + vy.w;
    float4 bp = ((const float4*)bproj)[tid];
    float4 xo;
    xo.x = v.x + bp.x; xo.y = v.y + bp.y; xo.z = v.z + bp.z; xo.w = v.w + bp.w;
    ((float4*)(xout + row * C_DIM))[tid] = xo;   // reduce_kernel adds PROJ partials onto this
    float s  = v.x + v.y + v.z + v.w;
    float sq = v.x * v.x + v.y * v.y + v.z * v.z + v.w * v.w;
#pragma unroll
    for (int off = 32; off > 0; off >>= 1) {
        s  += __shfl_down(s, off, 64);
        sq += __shfl_down(sq, off, 64);
    }
    __shared__ float rs[4], rq[4];
    int wv = tid >> 6, ln = tid & 63;
    if (ln == 0) { rs[wv] = s; rq[wv] = sq; }
    __syncthreads();
    s = rs[0] + rs[1] + rs[2] + rs[3];
    sq = rq[0] + rq[1] + rq[2] + rq[3];
    float mean = s * (1.f / C_DIM);
    float rstd = rsqrtf(sq * (1.f / C_DIM) - mean * mean + 1e-5f);
    float4 wv4 = ((const float4*)w)[tid];
    float4 bv4 = ((const float4*)b)[tid];
    s16x4 o;
    o[0] = f2bf((v.x - mean) * rstd * wv4.x + bv4.x);
    o[1] = f2bf((v.y - mean) * rstd * wv4.y + bv4.y);
    o[2] = f2bf((v.z - mean) * rstd * wv4.z + bv4.z);
    o[3] = f2bf((v.w - mean) * rstd * wv4.w + bv4.w);
    *(s16x4*)(out + row * C_DIM + tid * 4) = o;
}

// ---- split-K reduce: xout += sum of 4 bf16 partials (xout pre-init = x+y+b_proj) ----
__global__ __launch_bounds__(256) void reduce_kernel(
    const short* __restrict__ p, float* __restrict__ xout) {
    size_t i = (size_t)blockIdx.x * 256 + threadIdx.x;   // float4 index
    float4 a = ((const float4*)xout)[i];
#pragma unroll
    for (int c = 0; c < 4; c++) {
        s16x4 v = ((const s16x4*)(p + (size_t)c * 4194304))[i];
        a.x += bf2f(v[0]); a.y += bf2f(v[1]); a.z += bf2f(v[2]); a.w += bf2f(v[3]);
    }
    ((float4*)xout)[i] = a;
}

// ---------------- 256x256 2-phase GEMM (T3 minimum recipe; R13-proven) ----------
// MODE 0: fused QKV (q pre-scaled by 0.125*log2e for exp2-domain attn; packed vT);
// MODE 1: FC + tanh-form GELU (one exp2); MODE 2: split-K bf16 partials (no atomics).
template<int MODE>
__global__ __launch_bounds__(512, 1) void gemm2p(
    const short* __restrict__ A, const short* __restrict__ Bt,
    int K, int LDA, int N,
    const float* __restrict__ b0, const float* __restrict__ b1, const float* __restrict__ b2,
    short* __restrict__ os0, short* __restrict__ os1, short* __restrict__ os2,
    float* __restrict__ of0) {
    constexpr int MFR = 8, NFR = 4;                 // wave tile 128x64, 16x16 frags

    __shared__ short As[2][256 * 64];
    __shared__ short Bs[2][256 * 64];

    const int tid = threadIdx.x;
    const int wv = tid >> 6, lane = tid & 63, g = lane >> 4, r4 = lane & 15;
    const int wm = wv >> 2, wn = wv & 3;
    const int lr = lane >> 3, lc = lane & 7, sc = lc ^ lr;

    const int nwg = gridDim.x * gridDim.y;
    const int bid = blockIdx.y * gridDim.x + blockIdx.x;
    const int swz = (bid & 7) * (nwg >> 3) + (bid >> 3);   // bijective, nwg % 8 == 0
    const int m0 = (swz % gridDim.x) * 256;
    const int yy = swz / gridDim.x;
    int n0, kch;
    if constexpr (MODE == 2) {
        kch = yy >> 2;            // 4 K-chunks
        n0 = (yy & 3) * 256;      // N/256 = 4
    } else {
        kch = 0;
        n0 = yy * 256;
    }
    const size_t kbase = (size_t)kch * K;
    const size_t aoff = (size_t)m0 * LDA + kbase + sc * 8;
    const size_t boff = (size_t)n0 * LDA + kbase + sc * 8;

    const f32x4 zero4 = {0.f, 0.f, 0.f, 0.f};
    f32x4 acc[MFR][NFR];
#pragma unroll
    for (int i = 0; i < MFR; i++)
#pragma unroll
        for (int j = 0; j < NFR; j++) acc[i][j] = zero4;

    auto stage = [&](int bb, int t1) {
#pragma unroll
        for (int j = 0; j < 4; j++) {
            int rbase = j * 64 + wv * 8;
            gload16(A  + aoff + (size_t)(rbase + lr) * LDA + (size_t)t1 * 64, &As[bb][rbase * 64]);
            gload16(Bt + boff + (size_t)(rbase + lr) * LDA + (size_t)t1 * 64, &Bs[bb][rbase * 64]);
        }
    };

    stage(0, 0);
    __syncthreads();   // implicit vmcnt(0): tile 0 landed

    const int NT = K >> 6;
    int cur = 0;
    for (int t = 0; t < NT; ++t) {
        if (t + 1 < NT) stage(cur ^ 1, t + 1);   // issue BEFORE compute — hides under MFMA
        const char* Ac = (const char*)&As[cur][0];
        const char* Bc = (const char*)&Bs[cur][0];
#pragma unroll
        for (int kk = 0; kk < 2; kk++) {
            s16x8 aF[MFR], bF[NFR];
#pragma unroll
            for (int mf = 0; mf < MFR; mf++) {
                int row = wm * 128 + mf * 16 + r4;
                aF[mf] = *(const s16x8*)(Ac + ((row * 128 + kk * 64 + g * 16) ^ ((row & 7) << 4)));
            }
#pragma unroll
            for (int nf = 0; nf < NFR; nf++) {
                int row = wn * 64 + nf * 16 + r4;
                bF[nf] = *(const s16x8*)(Bc + ((row * 128 + kk * 64 + g * 16) ^ ((row & 7) << 4)));
            }
            PRIO1;
#pragma unroll
            for (int mf = 0; mf < MFR; mf++)
#pragma unroll
                for (int nf = 0; nf < NFR; nf++)
                    acc[mf][nf] = __builtin_amdgcn_mfma_f32_16x16x32_bf16(
                        aF[mf], bF[nf], acc[mf][nf], 0, 0, 0);
            PRIO0;
        }
        __syncthreads();   // ONE barrier/K-tile: drains vmcnt (tile t+1 visible) + frees buf[cur]
        cur ^= 1;
    }

    // epilogue: D layout col = lane&15, row = 4*(lane>>4)+r  [verified m89/m91]
#pragma unroll
    for (int mf = 0; mf < MFR; mf++) {
#pragma unroll
        for (int nf = 0; nf < NFR; nf++) {
            int n = n0 + wn * 64 + nf * 16 + r4;
            int mB = m0 + wm * 128 + mf * 16 + 4 * g;   // base m for r=0 (4 consecutive)
            if constexpr (MODE == 0) {
                int sel = n >> 10, nn = n & 1023;
                const float* bp = (sel == 0) ? b0 : ((sel == 1) ? b1 : b2);
                float bias = bp[nn];
                int h = nn >> 6, d = nn & 63;
                int bb2 = mB >> 11, tt = mB & 2047;
                size_t qz = ((size_t)(bb2 * HEADS + h) * T_SEQ + tt) * HD + d;
                if (sel == 0) {
                    // q consumed only by attn: pre-scale by 0.125*log2(e) (exp2-domain softmax)
#pragma unroll
                    for (int r = 0; r < 4; r++)
                        os0[qz + (size_t)r * HD] = f2bf((acc[mf][nf][r] + bias) * 0.18033688f);
                } else if (sel == 1) {
#pragma unroll
                    for (int r = 0; r < 4; r++) {
                        float val = acc[mf][nf][r] + bias;
                        os1[qz + (size_t)r * HD] = f2bf(val);
                        of0[qz + (size_t)r * HD] = val;            // kout
                    }
                } else {
                    s16x4 vp;
#pragma unroll
                    for (int r = 0; r < 4; r++) {
                        float val = acc[mf][nf][r] + bias;
                        of0[4194304 + qz + (size_t)r * HD] = val;  // vout
                        vp[r] = f2bf(val);
                    }
                    *(s16x4*)&os2[((size_t)(bb2 * HEADS + h) * HD + d) * T_SEQ + tt] = vp;
                }
            } else if constexpr (MODE == 1) {
                float bias = b0[n];
#pragma unroll
                for (int r = 0; r < 4; r++) {
                    float val = acc[mf][nf][r] + bias;
                    // tanh-form GELU: val * e/(e+1), e = exp2(2*log2e*0.79788456*(v+0.044715 v^3))
                    float u = val * (0.7978845608f + 0.0356774081f * val * val);
                    float e = exp2f(fminf(u * 2.885390082f, 126.f));
                    val = val * (e / (e + 1.f));
                    os0[(size_t)(mB + r) * N + n] = f2bf(val);
                }
            } else {
#pragma unroll
                for (int r = 0; r < 4; r++)
                    os0[(size_t)kch * 4194304 + (size_t)(mB + r) * N + n] = f2bf(acc[mf][nf][r]);
            }
        }
    }
}

// ---------------- causal flash attention — 4-wave 48KB blocks, 2/CU, XCD head-banding --------
// grid (16, 32), 256 threads (4 waves). Each block owns a full 128-row q-tile and walks ALL
// its kv tiles: nst = 2*qtr+2 tiles of 64 (R19 BUGFIX: previously qtr+1 — half the context).
// Causal mask active on the last two tiles (st >= 2*qtr). LDS = K dbuf 16KB + V dbuf 16KB +
// P 16KB = 49152 B -> 2 independent blocks/CU (no merge, no lockstep; stalls overlap).
// XCD remap: linear = by*16+bx; xcd = linear&7; slot = linear>>3; bh = xcd*4 + (slot&3);
// work bx = slot>>2 (bijective; K/V band 2MB per XCD L2). Balanced pairing: phases
// qtr = {15-bx, bx} -> (2*(15-bx)+2) + (2*bx+2) = 34 uniform steps per block.
// Wave w handles q rows w*32..w*32+31 (2 qh-sets sharing one K/V frag read).
// Q pre-scaled; exp2-domain softmax + defer-max; mask -3e38.
__global__ __launch_bounds__(256) void attn_kernel(
    const short* __restrict__ qb, const short* __restrict__ kb,
    const short* __restrict__ vtb, float* __restrict__ y) {
    __shared__ short Ks[2][64 * 64];   // K double buffer, 8KB each
    __shared__ short Vs[2][64 * 64];   // V double buffer
    __shared__ short Ps[4][32 * 64];   // per-wave P tile (4KB)

    int linear = blockIdx.y * gridDim.x + blockIdx.x;
    int xcd = linear & 7, slot = linear >> 3;
    int bh = xcd * 4 + (slot & 3);        // head band per XCD
    int bx = slot >> 2;                   // 0..15 within band
    int tid = threadIdx.x, w = tid >> 6, lane = tid & 63, g = lane >> 4, r4 = lane & 15;
    int wq = w;                           // 4 waves x 32 q rows
    int lr = lane >> 3, lc = lane & 7, sc = lc ^ lr;
    const f32x4 zero4 = {0.f, 0.f, 0.f, 0.f};

    for (int ph = 0; ph < 2; ++ph) {
        int qtr = ph ? bx : (15 - bx);
        int qbase = qtr * 128;
        int nst = 2 * qtr + 2;            // kv tiles of 64 covering [0, (qtr+1)*128)

        const short* Qp = qb + ((size_t)bh * T_SEQ + qbase + wq * 32 + r4) * HD;
        s16x8 qf[2][2];
        qf[0][0] = *(const s16x8*)&Qp[g * 8];
        qf[0][1] = *(const s16x8*)&Qp[32 + g * 8];
        qf[1][0] = *(const s16x8*)&Qp[16 * HD + g * 8];
        qf[1][1] = *(const s16x8*)&Qp[16 * HD + 32 + g * 8];

        f32x4 yacc[2][4];
#pragma unroll
        for (int qh = 0; qh < 2; qh++)
#pragma unroll
            for (int ni = 0; ni < 4; ni++) yacc[qh][ni] = zero4;
        float mrun[2] = {-1e30f, -1e30f}, lrun[2] = {0.f, 0.f};

        // prologue: stage tile 0 into buf 0 (4 waves cover 64 rows: 16 rows each)
#pragma unroll
        for (int j = 0; j < 2; j++) {
            int rw = (wq * 2 + j) * 8 + lr;
            gload16(kb  + ((size_t)bh * T_SEQ + rw) * HD + sc * 8, &Ks[0][(wq * 2 + j) * 512]);
            gload16(vtb + ((size_t)bh * HD + rw) * T_SEQ + sc * 8, &Vs[0][(wq * 2 + j) * 512]);
        }
        VMCNT0;
        __syncthreads();

        for (int st = 0; st < nst; ++st) {
            int cur = st & 1;
            int s0 = st * 64;
            if (st + 1 < nst) {   // prefetch next tile into other buffer
#pragma unroll
                for (int j = 0; j < 2; j++) {
                    int rw = (wq * 2 + j) * 8 + lr;
                    gload16(kb  + ((size_t)bh * T_SEQ + s0 + 64 + rw) * HD + sc * 8,
                            &Ks[cur ^ 1][(wq * 2 + j) * 512]);
                    gload16(vtb + ((size_t)bh * HD + rw) * T_SEQ + s0 + 64 + sc * 8,
                            &Vs[cur ^ 1][(wq * 2 + j) * 512]);
                }
            }
            // ---- S^T = K Q^T for both qh sets; kf read ONCE per (kk,sb)
            f32x4 sacc[2][4];
#pragma unroll
            for (int qh = 0; qh < 2; qh++)
#pragma unroll
                for (int sb = 0; sb < 4; sb++) sacc[qh][sb] = zero4;
            PRIO1;
#pragma unroll
            for (int kk = 0; kk < 2; kk++) {
#pragma unroll
                for (int sb = 0; sb < 4; sb++) {
                    int srow = sb * 16 + r4;
                    s16x8 kf = *(const s16x8*)((const char*)&Ks[cur][0] +
                                ((srow * 128 + kk * 64 + g * 16) ^ ((r4 & 7) << 4)));
                    sacc[0][sb] = __builtin_amdgcn_mfma_f32_16x16x32_bf16(kf, qf[0][kk], sacc[0][sb], 0, 0, 0);
                    sacc[1][sb] = __builtin_amdgcn_mfma_f32_16x16x32_bf16(kf, qf[1][kk], sacc[1][sb], 0, 0, 0);
                }
            }
            PRIO0;
            // ---- online softmax per qh set (lane owns q = qbase + wq*32 + qh*16 + r4)
            bool diag = (st >= 2 * qtr);   // last two tiles straddle the causal diagonal
            float p[2][4][4];
#pragma unroll
            for (int qh = 0; qh < 2; qh++) {
                float mx = -3e38f;
#pragma unroll
                for (int sb = 0; sb < 4; sb++)
#pragma unroll
                    for (int r = 0; r < 4; r++) {
                        float v = sacc[qh][sb][r];
                        if (diag) {
                            int kv = s0 + sb * 16 + 4 * g + r;
                            int qg = qbase + wq * 32 + qh * 16 + r4;
                            if (kv > qg) v = -3e38f;
                        }
                        p[qh][sb][r] = v;
                        mx = fmaxf(mx, v);
                    }
                mx = fmaxf(mx, __shfl_xor(mx, 16, 64));
                mx = fmaxf(mx, __shfl_xor(mx, 32, 64));
                if (!__all(mx <= mrun[qh] + 8.f)) {
                    float mnew = fmaxf(mrun[qh], mx);
                    float alpha = exp2f(mrun[qh] - mnew);
                    float aC[4];
#pragma unroll
                    for (int r = 0; r < 4; r++) aC[r] = __shfl(alpha, 4 * g + r, 64);
#pragma unroll
                    for (int ni = 0; ni < 4; ni++)
#pragma unroll
                        for (int r = 0; r < 4; r++) yacc[qh][ni][r] *= aC[r];
                    lrun[qh] *= alpha;
                    mrun[qh] = mnew;
                }
                float rsum = 0.f;
#pragma unroll
                for (int sb = 0; sb < 4; sb++)
#pragma unroll
                    for (int r = 0; r < 4; r++) {
                        float e = exp2f(p[qh][sb][r] - mrun[qh]);
                        p[qh][sb][r] = e;
                        rsum += e;
                    }
                rsum += __shfl_xor(rsum, 16, 64);
                rsum += __shfl_xor(rsum, 32, 64);
                lrun[qh] += rsum;
                // P -> per-wave LDS (row = qh*16 + r4; row&7 == r4&7)
#pragma unroll
                for (int sb = 0; sb < 4; sb++) {
                    s16x4 pk;
#pragma unroll
                    for (int r = 0; r < 4; r++) pk[r] = f2bf(p[qh][sb][r]);
                    int off = (((qh * 16 + r4) * 128) + (sb * 16 + 4 * g) * 2) ^ ((r4 & 7) << 4);
                    *(s16x4*)((char*)&Ps[w][0] + off) = pk;
                }
            }
            // ---- Y += P V for both qh sets; vb read ONCE per (kk,ni)
            PRIO1;
#pragma unroll
            for (int kk = 0; kk < 2; kk++) {
                s16x8 pf[2];
#pragma unroll
                for (int qh = 0; qh < 2; qh++)
                    pf[qh] = *(const s16x8*)((const char*)&Ps[w][0] +
                              ((((qh * 16 + r4) * 128) + kk * 64 + g * 16) ^ ((r4 & 7) << 4)));
#pragma unroll
                for (int ni = 0; ni < 4; ni++) {
                    int vrow = ni * 16 + r4;
                    s16x8 vb = *(const s16x8*)((const char*)&Vs[cur][0] +
                                ((vrow * 128 + kk * 64 + g * 16) ^ ((r4 & 7) << 4)));
                    yacc[0][ni] = __builtin_amdgcn_mfma_f32_16x16x32_bf16(pf[0], vb, yacc[0][ni], 0, 0, 0);
                    yacc[1][ni] = __builtin_amdgcn_mfma_f32_16x16x32_bf16(pf[1], vb, yacc[1][ni], 0, 0, 0);
                }
            }
            PRIO0;
            VMCNT0;          // prefetch landed (own)
            __syncthreads(); // all waves done with buf[cur]; buf[cur^1] published
        }
        // epilogue: write this wave's 32 q rows directly (no merge)
        int bb = bh >> 4, h = bh & 15;
#pragma unroll
        for (int qh = 0; qh < 2; qh++) {
            float lC[4];
#pragma unroll
            for (int r = 0; r < 4; r++) lC[r] = __shfl(lrun[qh], 4 * g + r, 64);
#pragma unroll
            for (int ni = 0; ni < 4; ni++)
#pragma unroll
                for (int r = 0; r < 4; r++) {
                    int q = qbase + wq * 32 + qh * 16 + 4 * g + r;
                    y[((size_t)bb * T_SEQ + q) * C_DIM + h * HD + ni * 16 + r4] =
                        yacc[qh][ni][r] / lC[r];
                }
        }
        __syncthreads();   // phase A fully done (incl. LDS reads) before phase B restages
    }
}

extern "C" void kernel_launch(void* const* d_in, const int* in_sizes, int n_in,
                              void* d_out, int out_size, void* d_ws, size_t ws_size,
                              hipStream_t stream) {
    (void)in_sizes; (void)n_in; (void)out_size; (void)ws_size;
    const float* x    = (const float*)d_in[0];
    const float* wq   = (const float*)d_in[1];
    const float* bq   = (const float*)d_in[2];
    const float* wk   = (const float*)d_in[3];
    const float* bk   = (const float*)d_in[4];
    const float* wvp  = (const float*)d_in[5];
    const float* bv   = (const float*)d_in[6];
    const float* ln1w = (const float*)d_in[7];
    const float* ln1b = (const float*)d_in[8];
    const float* ln2w = (const float*)d_in[9];
    const float* ln2b = (const float*)d_in[10];
    const float* wfc  = (const float*)d_in[11];
    const float* bfc  = (const float*)d_in[12];
    const float* wpr  = (const float*)d_in[13];
    const float* bpr  = (const float*)d_in[14];

    float* xout = (float*)d_out;                 // [2,2048,1024]
    float* kout = xout + 4194304;                // [2,16,2048,64] (vout = kout + 4194304)

    // workspace layout (~124 MB)
    short* wqkvt = (short*)d_ws;                 // [3072][1024] bf16
    short* wfct  = wqkvt + 3072 * 1024;          // [4096][1024]
    short* wprt  = wfct + 4096 * 1024;           // [1024][4096]
    short* hb    = wprt + 1024 * 4096;           // LN1 out bf16 [4096][1024]
    short* qb    = hb + 4096 * 1024;             // Q bf16 [B,H,T,D] (pre-scaled)
    short* kbuf  = qb + 4096 * 1024;             // K bf16 [B,H,T,D]
    short* vtb   = kbuf + 4096 * 1024;           // V bf16 transposed [B,H,D,T]
    short* h2b   = vtb + 4096 * 1024;            // LN2 out bf16
    short* fcb   = h2b + 4096 * 1024;            // gelu(fc) bf16 [4096][4096]
    float* ybuf  = (float*)(fcb + 4096 * 4096);  // attn out fp32 [4096][1024]
    short* pbuf  = qb;                           // PROJ partials: 4 x 8MB bf16 (qb..h2b dead)

    // fused transposes + LN1
    prep_kernel<<<15360, 256, 0, stream>>>(wq, wk, wvp, wfc, wpr,
        wqkvt, wfct, wprt, x, ln1w, ln1b, hb);

    // fused QKV GEMM: M=4096, N=3072, K=1024 — 256² 2-phase, grid 16x12 = 192
    gemm2p<0><<<dim3(16, 12), 512, 0, stream>>>(hb, wqkvt, 1024, 1024, 3072,
        bq, bk, bv, qb, kbuf, vtb, kout);

    // attention: 512 blocks x 4 waves, 48KB LDS -> 2 independent blocks/CU; XCD head-banding
    attn_kernel<<<dim3(16, 32), 256, 0, stream>>>(qb, kbuf, vtb, ybuf);

    // x+y residual, LN2, and xout init (= x+y+b_proj)
    resln_kernel<<<4096, 256, 0, stream>>>(x, ybuf, ln2w, ln2b, bpr, h2b, xout);

    // MLP fc + gelu: M=4096, N=4096, K=1024 — 256² 2-phase, grid 16x16 = 256
    gemm2p<1><<<dim3(16, 16), 512, 0, stream>>>(h2b, wfct, 1024, 1024, 4096,
        bfc, nullptr, nullptr, fcb, nullptr, nullptr, nullptr);

    // MLP proj, split-K=4 (K-chunks of 1024), bf16 partials — 256² 2-phase, grid 16x16 = 256
    gemm2p<2><<<dim3(16, 16), 512, 0, stream>>>(fcb, wprt, 1024, 4096, 1024,
        nullptr, nullptr, nullptr, pbuf, nullptr, nullptr, nullptr);

    // xout += sum of partials
    reduce_kernel<<<4096, 256, 0, stream>>>(pbuf, xout);
}

// Round 21
// 225.731 us; speedup vs baseline: 1.1941x; 1.1941x over previous
//
#include <hip/hip_runtime.h>
#include <hip/hip_bf16.h>

// Transformer block fwd: B=2, T=2048, C=1024, H=16, D=64.
// out = concat(x_out fp32 [2,2048,1024], k fp32 [2,16,2048,64], v fp32 [2,16,2048,64])
// R21 = R18 restoration (best measured: 224.9 us).

#define T_SEQ 2048
#define C_DIM 1024
#define HEADS 16
#define HD    64

typedef __attribute__((ext_vector_type(8))) short s16x8;   // 8 x bf16 (4 VGPR) — MFMA A/B frag
typedef __attribute__((ext_vector_type(4))) short s16x4;
typedef __attribute__((ext_vector_type(4))) float f32x4;   // MFMA C/D frag

__device__ __forceinline__ short f2bf(float f) {
    union { __hip_bfloat16 h; short s; } u;
    u.h = __float2bfloat16(f);
    return u.s;
}
__device__ __forceinline__ float bf2f(short s) {
    union { float f; unsigned u; } u;
    u.u = ((unsigned)(unsigned short)s) << 16;
    return u.f;
}

// async global->LDS, 16B per lane. LDS dest = wave-uniform base + lane*16 (linear).
__device__ __forceinline__ void gload16(const void* g, void* l) {
    __builtin_amdgcn_global_load_lds(
        (const __attribute__((address_space(1))) void*)g,
        (__attribute__((address_space(3))) void*)l, 16, 0, 0);
}
#define VMCNT0 asm volatile("s_waitcnt vmcnt(0)" ::: "memory")
#define PRIO1  __builtin_amdgcn_s_setprio(1)
#define PRIO0  __builtin_amdgcn_s_setprio(0)

// ---------------- fused prep: 5 weight transposes (fp32 -> bf16, [K][N] -> [N][K]) + LN1 ----
__global__ __launch_bounds__(256) void prep_kernel(
    const float* __restrict__ wq, const float* __restrict__ wk, const float* __restrict__ wv,
    const float* __restrict__ wfc, const float* __restrict__ wpr,
    short* __restrict__ wqkvt, short* __restrict__ wfct, short* __restrict__ wprt,
    const float* __restrict__ x, const float* __restrict__ ln1w, const float* __restrict__ ln1b,
    short* __restrict__ hb) {
    int b = blockIdx.x, tid = threadIdx.x;
    if (b < 11264) {
        const float* W; short* Wt; int K, N, n0, k0;
        if (b < 3072) {
            int which = b >> 10, sub = b & 1023;
            W = (which == 0) ? wq : ((which == 1) ? wk : wv);
            Wt = wqkvt + which * 1024 * 1024;
            K = 1024; N = 1024;
            n0 = (sub & 31) * 32; k0 = (sub >> 5) * 32;
        } else if (b < 7168) {
            int sub = b - 3072;
            W = wfc; Wt = wfct; K = 1024; N = 4096;
            n0 = (sub & 127) * 32; k0 = (sub >> 7) * 32;
        } else {
            int sub = b - 7168;
            W = wpr; Wt = wprt; K = 4096; N = 1024;
            n0 = (sub & 31) * 32; k0 = (sub >> 5) * 32;
        }
        __shared__ float t[32][33];
        int ty = tid >> 3, tx = tid & 7;
        float4 v = *(const float4*)&W[(size_t)(k0 + ty) * N + n0 + tx * 4];
        t[ty][tx * 4 + 0] = v.x; t[ty][tx * 4 + 1] = v.y;
        t[ty][tx * 4 + 2] = v.z; t[ty][tx * 4 + 3] = v.w;
        __syncthreads();
        int r = tid >> 3, c = tid & 7;
        s16x4 o;
#pragma unroll
        for (int j = 0; j < 4; j++) o[j] = f2bf(t[c * 4 + j][r]);
        *(s16x4*)&Wt[(size_t)(n0 + r) * K + k0 + c * 4] = o;
    } else {
        int row = b - 11264;
        float4 v = ((const float4*)(x + (size_t)row * C_DIM))[tid];
        float s  = v.x + v.y + v.z + v.w;
        float sq = v.x * v.x + v.y * v.y + v.z * v.z + v.w * v.w;
#pragma unroll
        for (int off = 32; off > 0; off >>= 1) {
            s  += __shfl_down(s, off, 64);
            sq += __shfl_down(sq, off, 64);
        }
        __shared__ float rs[4], rq[4];
        int wv2 = tid >> 6, ln = tid & 63;
        if (ln == 0) { rs[wv2] = s; rq[wv2] = sq; }
        __syncthreads();
        s = rs[0] + rs[1] + rs[2] + rs[3];
        sq = rq[0] + rq[1] + rq[2] + rq[3];
        float mean = s * (1.f / C_DIM);
        float rstd = rsqrtf(sq * (1.f / C_DIM) - mean * mean + 1e-5f);
        float4 wv4 = ((const float4*)ln1w)[tid];
        float4 bv4 = ((const float4*)ln1b)[tid];
        s16x4 o;
        o[0] = f2bf((v.x - mean) * rstd * wv4.x + bv4.x);
        o[1] = f2bf((v.y - mean) * rstd * wv4.y + bv4.y);
        o[2] = f2bf((v.z - mean) * rstd * wv4.z + bv4.z);
        o[3] = f2bf((v.w - mean) * rstd * wv4.w + bv4.w);
        *(s16x4*)(hb + (size_t)row * C_DIM + tid * 4) = o;
    }
}

// ---- residual + LN2 + PROJ-output init: xout = x+y+b_proj (fp32), h2 = LN(x+y) bf16 ----
__global__ __launch_bounds__(256) void resln_kernel(
    const float* __restrict__ x, const float* __restrict__ y,
    const float* __restrict__ w, const float* __restrict__ b,
    const float* __restrict__ bproj,
    short* __restrict__ out, float* __restrict__ xout) {
    int row = blockIdx.x, tid = threadIdx.x;
    float4 vx = ((const float4*)(x + row * C_DIM))[tid];
    float4 vy = ((const float4*)(y + row * C_DIM))[tid];
    float4 v;
    v.x = vx.x + vy.x; v.y = vx.y + vy.y; v.z = vx.z + vy.z; v.w = vx.w + vy.w;
    float4 bp = ((const float4*)bproj)[tid];
    float4 xo;
    xo.x = v.x + bp.x; xo.y = v.y + bp.y; xo.z = v.z + bp.z; xo.w = v.w + bp.w;
    ((float4*)(xout + row * C_DIM))[tid] = xo;   // reduce_kernel adds PROJ partials onto this
    float s  = v.x + v.y + v.z + v.w;
    float sq = v.x * v.x + v.y * v.y + v.z * v.z + v.w * v.w;
#pragma unroll
    for (int off = 32; off > 0; off >>= 1) {
        s  += __shfl_down(s, off, 64);
        sq += __shfl_down(sq, off, 64);
    }
    __shared__ float rs[4], rq[4];
    int wv = tid >> 6, ln = tid & 63;
    if (ln == 0) { rs[wv] = s; rq[wv] = sq; }
    __syncthreads();
    s = rs[0] + rs[1] + rs[2] + rs[3];
    sq = rq[0] + rq[1] + rq[2] + rq[3];
    float mean = s * (1.f / C_DIM);
    float rstd = rsqrtf(sq * (1.f / C_DIM) - mean * mean + 1e-5f);
    float4 wv4 = ((const float4*)w)[tid];
    float4 bv4 = ((const float4*)b)[tid];
    s16x4 o;
    o[0] = f2bf((v.x - mean) * rstd * wv4.x + bv4.x);
    o[1] = f2bf((v.y - mean) * rstd * wv4.y + bv4.y);
    o[2] = f2bf((v.z - mean) * rstd * wv4.z + bv4.z);
    o[3] = f2bf((v.w - mean) * rstd * wv4.w + bv4.w);
    *(s16x4*)(out + row * C_DIM + tid * 4) = o;
}

// ---- split-K reduce: xout += sum of 4 bf16 partials (xout pre-init = x+y+b_proj) ----
__global__ __launch_bounds__(256) void reduce_kernel(
    const short* __restrict__ p, float* __restrict__ xout) {
    size_t i = (size_t)blockIdx.x * 256 + threadIdx.x;   // float4 index
    float4 a = ((const float4*)xout)[i];
#pragma unroll
    for (int c = 0; c < 4; c++) {
        s16x4 v = ((const s16x4*)(p + (size_t)c * 4194304))[i];
        a.x += bf2f(v[0]); a.y += bf2f(v[1]); a.z += bf2f(v[2]); a.w += bf2f(v[3]);
    }
    ((float4*)xout)[i] = a;
}

// ---------------- 256x256 2-phase GEMM (T3 minimum recipe; R13-proven) ----------
// MODE 0: fused QKV (q pre-scaled by 0.125*log2e for exp2-domain attn; packed vT);
// MODE 1: FC + tanh-form GELU (one exp2); MODE 2: split-K bf16 partials (no atomics).
template<int MODE>
__global__ __launch_bounds__(512, 1) void gemm2p(
    const short* __restrict__ A, const short* __restrict__ Bt,
    int K, int LDA, int N,
    const float* __restrict__ b0, const float* __restrict__ b1, const float* __restrict__ b2,
    short* __restrict__ os0, short* __restrict__ os1, short* __restrict__ os2,
    float* __restrict__ of0) {
    constexpr int MFR = 8, NFR = 4;                 // wave tile 128x64, 16x16 frags

    __shared__ short As[2][256 * 64];
    __shared__ short Bs[2][256 * 64];

    const int tid = threadIdx.x;
    const int wv = tid >> 6, lane = tid & 63, g = lane >> 4, r4 = lane & 15;
    const int wm = wv >> 2, wn = wv & 3;
    const int lr = lane >> 3, lc = lane & 7, sc = lc ^ lr;

    const int nwg = gridDim.x * gridDim.y;
    const int bid = blockIdx.y * gridDim.x + blockIdx.x;
    const int swz = (bid & 7) * (nwg >> 3) + (bid >> 3);   // bijective, nwg % 8 == 0
    const int m0 = (swz % gridDim.x) * 256;
    const int yy = swz / gridDim.x;
    int n0, kch;
    if constexpr (MODE == 2) {
        kch = yy >> 2;            // 4 K-chunks
        n0 = (yy & 3) * 256;      // N/256 = 4
    } else {
        kch = 0;
        n0 = yy * 256;
    }
    const size_t kbase = (size_t)kch * K;
    const size_t aoff = (size_t)m0 * LDA + kbase + sc * 8;
    const size_t boff = (size_t)n0 * LDA + kbase + sc * 8;

    const f32x4 zero4 = {0.f, 0.f, 0.f, 0.f};
    f32x4 acc[MFR][NFR];
#pragma unroll
    for (int i = 0; i < MFR; i++)
#pragma unroll
        for (int j = 0; j < NFR; j++) acc[i][j] = zero4;

    auto stage = [&](int bb, int t1) {
#pragma unroll
        for (int j = 0; j < 4; j++) {
            int rbase = j * 64 + wv * 8;
            gload16(A  + aoff + (size_t)(rbase + lr) * LDA + (size_t)t1 * 64, &As[bb][rbase * 64]);
            gload16(Bt + boff + (size_t)(rbase + lr) * LDA + (size_t)t1 * 64, &Bs[bb][rbase * 64]);
        }
    };

    stage(0, 0);
    __syncthreads();   // implicit vmcnt(0): tile 0 landed

    const int NT = K >> 6;
    int cur = 0;
    for (int t = 0; t < NT; ++t) {
        if (t + 1 < NT) stage(cur ^ 1, t + 1);   // issue BEFORE compute — hides under MFMA
        const char* Ac = (const char*)&As[cur][0];
        const char* Bc = (const char*)&Bs[cur][0];
#pragma unroll
        for (int kk = 0; kk < 2; kk++) {
            s16x8 aF[MFR], bF[NFR];
#pragma unroll
            for (int mf = 0; mf < MFR; mf++) {
                int row = wm * 128 + mf * 16 + r4;
                aF[mf] = *(const s16x8*)(Ac + ((row * 128 + kk * 64 + g * 16) ^ ((row & 7) << 4)));
            }
#pragma unroll
            for (int nf = 0; nf < NFR; nf++) {
                int row = wn * 64 + nf * 16 + r4;
                bF[nf] = *(const s16x8*)(Bc + ((row * 128 + kk * 64 + g * 16) ^ ((row & 7) << 4)));
            }
            PRIO1;
#pragma unroll
            for (int mf = 0; mf < MFR; mf++)
#pragma unroll
                for (int nf = 0; nf < NFR; nf++)
                    acc[mf][nf] = __builtin_amdgcn_mfma_f32_16x16x32_bf16(
                        aF[mf], bF[nf], acc[mf][nf], 0, 0, 0);
            PRIO0;
        }
        __syncthreads();   // ONE barrier/K-tile: drains vmcnt (tile t+1 visible) + frees buf[cur]
        cur ^= 1;
    }

    // epilogue: D layout col = lane&15, row = 4*(lane>>4)+r  [verified m89/m91]
#pragma unroll
    for (int mf = 0; mf < MFR; mf++) {
#pragma unroll
        for (int nf = 0; nf < NFR; nf++) {
            int n = n0 + wn * 64 + nf * 16 + r4;
            int mB = m0 + wm * 128 + mf * 16 + 4 * g;   // base m for r=0 (4 consecutive)
            if constexpr (MODE == 0) {
                int sel = n >> 10, nn = n & 1023;
                const float* bp = (sel == 0) ? b0 : ((sel == 1) ? b1 : b2);
                float bias = bp[nn];
                int h = nn >> 6, d = nn & 63;
                int bb2 = mB >> 11, tt = mB & 2047;
                size_t qz = ((size_t)(bb2 * HEADS + h) * T_SEQ + tt) * HD + d;
                if (sel == 0) {
                    // q consumed only by attn: pre-scale by 0.125*log2(e) (exp2-domain softmax)
#pragma unroll
                    for (int r = 0; r < 4; r++)
                        os0[qz + (size_t)r * HD] = f2bf((acc[mf][nf][r] + bias) * 0.18033688f);
                } else if (sel == 1) {
#pragma unroll
                    for (int r = 0; r < 4; r++) {
                        float val = acc[mf][nf][r] + bias;
                        os1[qz + (size_t)r * HD] = f2bf(val);
                        of0[qz + (size_t)r * HD] = val;            // kout
                    }
                } else {
                    s16x4 vp;
#pragma unroll
                    for (int r = 0; r < 4; r++) {
                        float val = acc[mf][nf][r] + bias;
                        of0[4194304 + qz + (size_t)r * HD] = val;  // vout
                        vp[r] = f2bf(val);
                    }
                    *(s16x4*)&os2[((size_t)(bb2 * HEADS + h) * HD + d) * T_SEQ + tt] = vp;
                }
            } else if constexpr (MODE == 1) {
                float bias = b0[n];
#pragma unroll
                for (int r = 0; r < 4; r++) {
                    float val = acc[mf][nf][r] + bias;
                    // tanh-form GELU: val * e/(e+1), e = exp2(2*log2e*0.79788456*(v+0.044715 v^3))
                    float u = val * (0.7978845608f + 0.0356774081f * val * val);
                    float e = exp2f(fminf(u * 2.885390082f, 126.f));
                    val = val * (e / (e + 1.f));
                    os0[(size_t)(mB + r) * N + n] = f2bf(val);
                }
            } else {
#pragma unroll
                for (int r = 0; r < 4; r++)
                    os0[(size_t)kch * 4194304 + (size_t)(mB + r) * N + n] = f2bf(acc[mf][nf][r]);
            }
        }
    }
}

// ---------------- causal flash attention — R18: 8 waves, kv-parity groups, XCD banding -------
// 256 blocks, 512 threads. XCD remap: linear = by*8+bx; xcd = linear&7; slot = linear>>3;
// bh = xcd*4 + (slot&3); bx = slot>>2 (bijective; K/V band 2MB per XCD L2 — FETCH 74->12MB).
// Wave w: q sub-tile wq = w&3 (32 q rows), kv-parity group g2 = w>>2 (tiles st = 2i+g2).
// Balanced pairing over 128-row q-tiles: phases qtr = {15-bx, bx}. K/V double-buffered per
// group; K/V frag reads SHARED across the wave's two qh-sets. End of phase: group merge via
// LDS overlays. Mask -3e38 (exp2(p-mrun)=0 even while mrun=-1e30).
__global__ __launch_bounds__(512) void attn_kernel(
    const short* __restrict__ qb, const short* __restrict__ kb,
    const short* __restrict__ vtb, float* __restrict__ y) {
    __shared__ short Ks[2][2][64 * 64];   // [group][buf]
    __shared__ short Vs[2][2][64 * 64];
    __shared__ short Ps[8][32 * 64];      // per-wave P tiles; overlaid as Ymrg during merge
    __shared__ float MLb[4][2][16][2];    // [wq][qh][r4][{m,l}] from group 1
    float* Ymrg = (float*)&Ps[0][0];      // [wq][32 rows][64 cols] fp32 = 8KB per wq

    int linear = blockIdx.y * gridDim.x + blockIdx.x;
    int xcd = linear & 7, slot = linear >> 3;
    int bh = xcd * 4 + (slot & 3);        // head band per XCD
    int bx = slot >> 2;                   // 0..7 within band
    int tid = threadIdx.x, w = tid >> 6, lane = tid & 63, g = lane >> 4, r4 = lane & 15;
    int wq = w & 3, g2 = w >> 2;
    int lr = lane >> 3, lc = lane & 7, sc = lc ^ lr;
    const f32x4 zero4 = {0.f, 0.f, 0.f, 0.f};

    for (int ph = 0; ph < 2; ++ph) {
        int qtr = ph ? bx : (15 - bx);
        int qbase = qtr * 128;

        const short* Qp = qb + ((size_t)bh * T_SEQ + qbase + wq * 32 + r4) * HD;
        s16x8 qf[2][2];
        qf[0][0] = *(const s16x8*)&Qp[g * 8];
        qf[0][1] = *(const s16x8*)&Qp[32 + g * 8];
        qf[1][0] = *(const s16x8*)&Qp[16 * HD + g * 8];
        qf[1][1] = *(const s16x8*)&Qp[16 * HD + 32 + g * 8];

        f32x4 yacc[2][4];
#pragma unroll
        for (int qh = 0; qh < 2; qh++)
#pragma unroll
            for (int ni = 0; ni < 4; ni++) yacc[qh][ni] = zero4;
        float mrun[2] = {-1e30f, -1e30f}, lrun[2] = {0.f, 0.f};

        // stage group tile i=0 (kv base g2*64) into buf 0
#pragma unroll
        for (int j = 0; j < 2; j++) {
            int rw = (wq * 2 + j) * 8 + lr;
            gload16(kb  + ((size_t)bh * T_SEQ + g2 * 64 + rw) * HD + sc * 8,
                    &Ks[g2][0][(wq * 2 + j) * 512]);
            gload16(vtb + ((size_t)bh * HD + rw) * T_SEQ + g2 * 64 + sc * 8,
                    &Vs[g2][0][(wq * 2 + j) * 512]);
        }
        VMCNT0;
        __syncthreads();

        for (int i = 0; i <= qtr; ++i) {
            int cur = i & 1;
            int s0 = (2 * i + g2) * 64;
            if (i + 1 <= qtr) {   // prefetch group's next tile (kv s0+128) into other buffer
#pragma unroll
                for (int j = 0; j < 2; j++) {
                    int rw = (wq * 2 + j) * 8 + lr;
                    gload16(kb  + ((size_t)bh * T_SEQ + s0 + 128 + rw) * HD + sc * 8,
                            &Ks[g2][cur ^ 1][(wq * 2 + j) * 512]);
                    gload16(vtb + ((size_t)bh * HD + rw) * T_SEQ + s0 + 128 + sc * 8,
                            &Vs[g2][cur ^ 1][(wq * 2 + j) * 512]);
                }
            }
            // ---- S^T = K Q^T for both qh sets; kf read ONCE per (kk,sb)
            f32x4 sacc[2][4];
#pragma unroll
            for (int qh = 0; qh < 2; qh++)
#pragma unroll
                for (int sb = 0; sb < 4; sb++) sacc[qh][sb] = zero4;
            PRIO1;
#pragma unroll
            for (int kk = 0; kk < 2; kk++) {
#pragma unroll
                for (int sb = 0; sb < 4; sb++) {
                    int srow = sb * 16 + r4;
                    s16x8 kf = *(const s16x8*)((const char*)&Ks[g2][cur][0] +
                                ((srow * 128 + kk * 64 + g * 16) ^ ((r4 & 7) << 4)));
                    sacc[0][sb] = __builtin_amdgcn_mfma_f32_16x16x32_bf16(kf, qf[0][kk], sacc[0][sb], 0, 0, 0);
                    sacc[1][sb] = __builtin_amdgcn_mfma_f32_16x16x32_bf16(kf, qf[1][kk], sacc[1][sb], 0, 0, 0);
                }
            }
            PRIO0;
            // ---- online softmax per qh set (lane owns q = qbase + wq*32 + qh*16 + r4)
            bool diag = (i == qtr);
            float p[2][4][4];
#pragma unroll
            for (int qh = 0; qh < 2; qh++) {
                float mx = -3e38f;
#pragma unroll
                for (int sb = 0; sb < 4; sb++)
#pragma unroll
                    for (int r = 0; r < 4; r++) {
                        float v = sacc[qh][sb][r];
                        if (diag) {
                            int kv = s0 + sb * 16 + 4 * g + r;
                            int qg = qbase + wq * 32 + qh * 16 + r4;
                            if (kv > qg) v = -3e38f;
                        }
                        p[qh][sb][r] = v;
                        mx = fmaxf(mx, v);
                    }
                mx = fmaxf(mx, __shfl_xor(mx, 16, 64));
                mx = fmaxf(mx, __shfl_xor(mx, 32, 64));
                if (!__all(mx <= mrun[qh] + 8.f)) {
                    float mnew = fmaxf(mrun[qh], mx);
                    float alpha = exp2f(mrun[qh] - mnew);
                    float aC[4];
#pragma unroll
                    for (int r = 0; r < 4; r++) aC[r] = __shfl(alpha, 4 * g + r, 64);
#pragma unroll
                    for (int ni = 0; ni < 4; ni++)
#pragma unroll
                        for (int r = 0; r < 4; r++) yacc[qh][ni][r] *= aC[r];
                    lrun[qh] *= alpha;
                    mrun[qh] = mnew;
                }
                float rsum = 0.f;
#pragma unroll
                for (int sb = 0; sb < 4; sb++)
#pragma unroll
                    for (int r = 0; r < 4; r++) {
                        float e = exp2f(p[qh][sb][r] - mrun[qh]);
                        p[qh][sb][r] = e;
                        rsum += e;
                    }
                rsum += __shfl_xor(rsum, 16, 64);
                rsum += __shfl_xor(rsum, 32, 64);
                lrun[qh] += rsum;
                // P -> per-wave LDS (row = qh*16 + r4; row&7 == r4&7)
#pragma unroll
                for (int sb = 0; sb < 4; sb++) {
                    s16x4 pk;
#pragma unroll
                    for (int r = 0; r < 4; r++) pk[r] = f2bf(p[qh][sb][r]);
                    int off = (((qh * 16 + r4) * 128) + (sb * 16 + 4 * g) * 2) ^ ((r4 & 7) << 4);
                    *(s16x4*)((char*)&Ps[w][0] + off) = pk;
                }
            }
            // ---- Y += P V for both qh sets; vb read ONCE per (kk,ni)
            PRIO1;
#pragma unroll
            for (int kk = 0; kk < 2; kk++) {
                s16x8 pf[2];
#pragma unroll
                for (int qh = 0; qh < 2; qh++)
                    pf[qh] = *(const s16x8*)((const char*)&Ps[w][0] +
                              ((((qh * 16 + r4) * 128) + kk * 64 + g * 16) ^ ((r4 & 7) << 4)));
#pragma unroll
                for (int ni = 0; ni < 4; ni++) {
                    int vrow = ni * 16 + r4;
                    s16x8 vb = *(const s16x8*)((const char*)&Vs[g2][cur][0] +
                                ((vrow * 128 + kk * 64 + g * 16) ^ ((r4 & 7) << 4)));
                    yacc[0][ni] = __builtin_amdgcn_mfma_f32_16x16x32_bf16(pf[0], vb, yacc[0][ni], 0, 0, 0);
                    yacc[1][ni] = __builtin_amdgcn_mfma_f32_16x16x32_bf16(pf[1], vb, yacc[1][ni], 0, 0, 0);
                }
            }
            PRIO0;
            VMCNT0;          // own staging landed
            __syncthreads(); // lockstep step boundary (both groups)
        }
        // ---- cross-group merge: group 1 publishes (m, l, yacc) via LDS
        if (g2 == 1) {
            if (g == 0) {
#pragma unroll
                for (int qh = 0; qh < 2; qh++) {
                    MLb[wq][qh][r4][0] = mrun[qh];
                    MLb[wq][qh][r4][1] = lrun[qh];
                }
            }
#pragma unroll
            for (int qh = 0; qh < 2; qh++)
#pragma unroll
                for (int ni = 0; ni < 4; ni++)
#pragma unroll
                    for (int r = 0; r < 4; r++)
                        Ymrg[wq * 2048 + (qh * 16 + 4 * g + r) * 64 + ni * 16 + r4] = yacc[qh][ni][r];
        }
        __syncthreads();
        if (g2 == 0) {
            int bb = bh >> 4, h = bh & 15;
#pragma unroll
            for (int qh = 0; qh < 2; qh++) {
                float m_b = MLb[wq][qh][r4][0], l_b = MLb[wq][qh][r4][1];
                float mM = fmaxf(mrun[qh], m_b);
                float fa = exp2f(mrun[qh] - mM), fb = exp2f(m_b - mM);
                float lM = lrun[qh] * fa + l_b * fb;
                float faC[4], fbC[4], lC[4];
#pragma unroll
                for (int r = 0; r < 4; r++) {
                    faC[r] = __shfl(fa, 4 * g + r, 64);
                    fbC[r] = __shfl(fb, 4 * g + r, 64);
                    lC[r]  = __shfl(lM, 4 * g + r, 64);
                }
#pragma unroll
                for (int ni = 0; ni < 4; ni++)
#pragma unroll
                    for (int r = 0; r < 4; r++) {
                        float yv = yacc[qh][ni][r] * faC[r] +
                                   Ymrg[wq * 2048 + (qh * 16 + 4 * g + r) * 64 + ni * 16 + r4] * fbC[r];
                        int q = qbase + wq * 32 + qh * 16 + 4 * g + r;
                        y[((size_t)bb * T_SEQ + q) * C_DIM + h * HD + ni * 16 + r4] = yv / lC[r];
                    }
            }
        }
        __syncthreads();   // merge reads done before next phase restages/rewrites
    }
}

extern "C" void kernel_launch(void* const* d_in, const int* in_sizes, int n_in,
                              void* d_out, int out_size, void* d_ws, size_t ws_size,
                              hipStream_t stream) {
    (void)in_sizes; (void)n_in; (void)out_size; (void)ws_size;
    const float* x    = (const float*)d_in[0];
    const float* wq   = (const float*)d_in[1];
    const float* bq   = (const float*)d_in[2];
    const float* wk   = (const float*)d_in[3];
    const float* bk   = (const float*)d_in[4];
    const float* wvp  = (const float*)d_in[5];
    const float* bv   = (const float*)d_in[6];
    const float* ln1w = (const float*)d_in[7];
    const float* ln1b = (const float*)d_in[8];
    const float* ln2w = (const float*)d_in[9];
    const float* ln2b = (const float*)d_in[10];
    const float* wfc  = (const float*)d_in[11];
    const float* bfc  = (const float*)d_in[12];
    const float* wpr  = (const float*)d_in[13];
    const float* bpr  = (const float*)d_in[14];

    float* xout = (float*)d_out;                 // [2,2048,1024]
    float* kout = xout + 4194304;                // [2,16,2048,64] (vout = kout + 4194304)

    // workspace layout (~124 MB)
    short* wqkvt = (short*)d_ws;                 // [3072][1024] bf16
    short* wfct  = wqkvt + 3072 * 1024;          // [4096][1024]
    short* wprt  = wfct + 4096 * 1024;           // [1024][4096]
    short* hb    = wprt + 1024 * 4096;           // LN1 out bf16 [4096][1024]
    short* qb    = hb + 4096 * 1024;             // Q bf16 [B,H,T,D] (pre-scaled)
    short* kbuf  = qb + 4096 * 1024;             // K bf16 [B,H,T,D]
    short* vtb   = kbuf + 4096 * 1024;           // V bf16 transposed [B,H,D,T]
    short* h2b   = vtb + 4096 * 1024;            // LN2 out bf16
    short* fcb   = h2b + 4096 * 1024;            // gelu(fc) bf16 [4096][4096]
    float* ybuf  = (float*)(fcb + 4096 * 4096);  // attn out fp32 [4096][1024]
    short* pbuf  = qb;                           // PROJ partials: 4 x 8MB bf16 (qb..h2b dead)

    // fused transposes + LN1
    prep_kernel<<<15360, 256, 0, stream>>>(wq, wk, wvp, wfc, wpr,
        wqkvt, wfct, wprt, x, ln1w, ln1b, hb);

    // fused QKV GEMM: M=4096, N=3072, K=1024 — 256² 2-phase, grid 16x12 = 192
    gemm2p<0><<<dim3(16, 12), 512, 0, stream>>>(hb, wqkvt, 1024, 1024, 3072,
        bq, bk, bv, qb, kbuf, vtb, kout);

    // attention: 256 blocks x 8 waves (R18 structure) + XCD head-banding remap
    attn_kernel<<<dim3(8, 32), 512, 0, stream>>>(qb, kbuf, vtb, ybuf);

    // x+y residual, LN2, and xout init (= x+y+b_proj)
    resln_kernel<<<4096, 256, 0, stream>>>(x, ybuf, ln2w, ln2b, bpr, h2b, xout);

    // MLP fc + gelu: M=4096, N=4096, K=1024 — 256² 2-phase, grid 16x16 = 256
    gemm2p<1><<<dim3(16, 16), 512, 0, stream>>>(h2b, wfct, 1024, 1024, 4096,
        bfc, nullptr, nullptr, fcb, nullptr, nullptr, nullptr);

    // MLP proj, split-K=4 (K-chunks of 1024), bf16 partials — 256² 2-phase, grid 16x16 = 256
    gemm2p<2><<<dim3(16, 16), 512, 0, stream>>>(fcb, wprt, 1024, 4096, 1024,
        nullptr, nullptr, nullptr, pbuf, nullptr, nullptr, nullptr);

    // xout += sum of partials
    reduce_kernel<<<4096, 256, 0, stream>>>(pbuf, xout);
}

// Round 22
// 218.919 us; speedup vs baseline: 1.2312x; 1.0311x over previous
//
#include <hip/hip_runtime.h>
#include <hip/hip_bf16.h>

// Transformer block fwd: B=2, T=2048, C=1024, H=16, D=64.
// out = concat(x_out fp32 [2,2048,1024], k fp32 [2,16,2048,64], v fp32 [2,16,2048,64])
// R22 = R18/R21 (best measured ~225 us) with setprio stripped from lockstep GEMM (m190).

#define T_SEQ 2048
#define C_DIM 1024
#define HEADS 16
#define HD    64

typedef __attribute__((ext_vector_type(8))) short s16x8;   // 8 x bf16 (4 VGPR) — MFMA A/B frag
typedef __attribute__((ext_vector_type(4))) short s16x4;
typedef __attribute__((ext_vector_type(4))) float f32x4;   // MFMA C/D frag

__device__ __forceinline__ short f2bf(float f) {
    union { __hip_bfloat16 h; short s; } u;
    u.h = __float2bfloat16(f);
    return u.s;
}
__device__ __forceinline__ float bf2f(short s) {
    union { float f; unsigned u; } u;
    u.u = ((unsigned)(unsigned short)s) << 16;
    return u.f;
}

// async global->LDS, 16B per lane. LDS dest = wave-uniform base + lane*16 (linear).
__device__ __forceinline__ void gload16(const void* g, void* l) {
    __builtin_amdgcn_global_load_lds(
        (const __attribute__((address_space(1))) void*)g,
        (__attribute__((address_space(3))) void*)l, 16, 0, 0);
}
#define VMCNT0 asm volatile("s_waitcnt vmcnt(0)" ::: "memory")
#define PRIO1  __builtin_amdgcn_s_setprio(1)
#define PRIO0  __builtin_amdgcn_s_setprio(0)

// ---------------- fused prep: 5 weight transposes (fp32 -> bf16, [K][N] -> [N][K]) + LN1 ----
__global__ __launch_bounds__(256) void prep_kernel(
    const float* __restrict__ wq, const float* __restrict__ wk, const float* __restrict__ wv,
    const float* __restrict__ wfc, const float* __restrict__ wpr,
    short* __restrict__ wqkvt, short* __restrict__ wfct, short* __restrict__ wprt,
    const float* __restrict__ x, const float* __restrict__ ln1w, const float* __restrict__ ln1b,
    short* __restrict__ hb) {
    int b = blockIdx.x, tid = threadIdx.x;
    if (b < 11264) {
        const float* W; short* Wt; int K, N, n0, k0;
        if (b < 3072) {
            int which = b >> 10, sub = b & 1023;
            W = (which == 0) ? wq : ((which == 1) ? wk : wv);
            Wt = wqkvt + which * 1024 * 1024;
            K = 1024; N = 1024;
            n0 = (sub & 31) * 32; k0 = (sub >> 5) * 32;
        } else if (b < 7168) {
            int sub = b - 3072;
            W = wfc; Wt = wfct; K = 1024; N = 4096;
            n0 = (sub & 127) * 32; k0 = (sub >> 7) * 32;
        } else {
            int sub = b - 7168;
            W = wpr; Wt = wprt; K = 4096; N = 1024;
            n0 = (sub & 31) * 32; k0 = (sub >> 5) * 32;
        }
        __shared__ float t[32][33];
        int ty = tid >> 3, tx = tid & 7;
        float4 v = *(const float4*)&W[(size_t)(k0 + ty) * N + n0 + tx * 4];
        t[ty][tx * 4 + 0] = v.x; t[ty][tx * 4 + 1] = v.y;
        t[ty][tx * 4 + 2] = v.z; t[ty][tx * 4 + 3] = v.w;
        __syncthreads();
        int r = tid >> 3, c = tid & 7;
        s16x4 o;
#pragma unroll
        for (int j = 0; j < 4; j++) o[j] = f2bf(t[c * 4 + j][r]);
        *(s16x4*)&Wt[(size_t)(n0 + r) * K + k0 + c * 4] = o;
    } else {
        int row = b - 11264;
        float4 v = ((const float4*)(x + (size_t)row * C_DIM))[tid];
        float s  = v.x + v.y + v.z + v.w;
        float sq = v.x * v.x + v.y * v.y + v.z * v.z + v.w * v.w;
#pragma unroll
        for (int off = 32; off > 0; off >>= 1) {
            s  += __shfl_down(s, off, 64);
            sq += __shfl_down(sq, off, 64);
        }
        __shared__ float rs[4], rq[4];
        int wv2 = tid >> 6, ln = tid & 63;
        if (ln == 0) { rs[wv2] = s; rq[wv2] = sq; }
        __syncthreads();
        s = rs[0] + rs[1] + rs[2] + rs[3];
        sq = rq[0] + rq[1] + rq[2] + rq[3];
        float mean = s * (1.f / C_DIM);
        float rstd = rsqrtf(sq * (1.f / C_DIM) - mean * mean + 1e-5f);
        float4 wv4 = ((const float4*)ln1w)[tid];
        float4 bv4 = ((const float4*)ln1b)[tid];
        s16x4 o;
        o[0] = f2bf((v.x - mean) * rstd * wv4.x + bv4.x);
        o[1] = f2bf((v.y - mean) * rstd * wv4.y + bv4.y);
        o[2] = f2bf((v.z - mean) * rstd * wv4.z + bv4.z);
        o[3] = f2bf((v.w - mean) * rstd * wv4.w + bv4.w);
        *(s16x4*)(hb + (size_t)row * C_DIM + tid * 4) = o;
    }
}

// ---- residual + LN2 + PROJ-output init: xout = x+y+b_proj (fp32), h2 = LN(x+y) bf16 ----
__global__ __launch_bounds__(256) void resln_kernel(
    const float* __restrict__ x, const float* __restrict__ y,
    const float* __restrict__ w, const float* __restrict__ b,
    const float* __restrict__ bproj,
    short* __restrict__ out, float* __restrict__ xout) {
    int row = blockIdx.x, tid = threadIdx.x;
    float4 vx = ((const float4*)(x + row * C_DIM))[tid];
    float4 vy = ((const float4*)(y + row * C_DIM))[tid];
    float4 v;
    v.x = vx.x + vy.x; v.y = vx.y + vy.y; v.z = vx.z + vy.z; v.w = vx.w + vy.w;
    float4 bp = ((const float4*)bproj)[tid];
    float4 xo;
    xo.x = v.x + bp.x; xo.y = v.y + bp.y; xo.z = v.z + bp.z; xo.w = v.w + bp.w;
    ((float4*)(xout + row * C_DIM))[tid] = xo;   // reduce_kernel adds PROJ partials onto this
    float s  = v.x + v.y + v.z + v.w;
    float sq = v.x * v.x + v.y * v.y + v.z * v.z + v.w * v.w;
#pragma unroll
    for (int off = 32; off > 0; off >>= 1) {
        s  += __shfl_down(s, off, 64);
        sq += __shfl_down(sq, off, 64);
    }
    __shared__ float rs[4], rq[4];
    int wv = tid >> 6, ln = tid & 63;
    if (ln == 0) { rs[wv] = s; rq[wv] = sq; }
    __syncthreads();
    s = rs[0] + rs[1] + rs[2] + rs[3];
    sq = rq[0] + rq[1] + rq[2] + rq[3];
    float mean = s * (1.f / C_DIM);
    float rstd = rsqrtf(sq * (1.f / C_DIM) - mean * mean + 1e-5f);
    float4 wv4 = ((const float4*)w)[tid];
    float4 bv4 = ((const float4*)b)[tid];
    s16x4 o;
    o[0] = f2bf((v.x - mean) * rstd * wv4.x + bv4.x);
    o[1] = f2bf((v.y - mean) * rstd * wv4.y + bv4.y);
    o[2] = f2bf((v.z - mean) * rstd * wv4.z + bv4.z);
    o[3] = f2bf((v.w - mean) * rstd * wv4.w + bv4.w);
    *(s16x4*)(out + row * C_DIM + tid * 4) = o;
}

// ---- split-K reduce: xout += sum of 4 bf16 partials (xout pre-init = x+y+b_proj) ----
__global__ __launch_bounds__(256) void reduce_kernel(
    const short* __restrict__ p, float* __restrict__ xout) {
    size_t i = (size_t)blockIdx.x * 256 + threadIdx.x;   // float4 index
    float4 a = ((const float4*)xout)[i];
#pragma unroll
    for (int c = 0; c < 4; c++) {
        s16x4 v = ((const s16x4*)(p + (size_t)c * 4194304))[i];
        a.x += bf2f(v[0]); a.y += bf2f(v[1]); a.z += bf2f(v[2]); a.w += bf2f(v[3]);
    }
    ((float4*)xout)[i] = a;
}

// ---------------- 256x256 2-phase GEMM (T3 minimum recipe; R13-proven) ----------
// setprio REMOVED (m190: T5 null-to-negative on barrier-lockstep structures).
// MODE 0: fused QKV (q pre-scaled by 0.125*log2e for exp2-domain attn; packed vT);
// MODE 1: FC + tanh-form GELU (one exp2); MODE 2: split-K bf16 partials (no atomics).
template<int MODE>
__global__ __launch_bounds__(512, 1) void gemm2p(
    const short* __restrict__ A, const short* __restrict__ Bt,
    int K, int LDA, int N,
    const float* __restrict__ b0, const float* __restrict__ b1, const float* __restrict__ b2,
    short* __restrict__ os0, short* __restrict__ os1, short* __restrict__ os2,
    float* __restrict__ of0) {
    constexpr int MFR = 8, NFR = 4;                 // wave tile 128x64, 16x16 frags

    __shared__ short As[2][256 * 64];
    __shared__ short Bs[2][256 * 64];

    const int tid = threadIdx.x;
    const int wv = tid >> 6, lane = tid & 63, g = lane >> 4, r4 = lane & 15;
    const int wm = wv >> 2, wn = wv & 3;
    const int lr = lane >> 3, lc = lane & 7, sc = lc ^ lr;

    const int nwg = gridDim.x * gridDim.y;
    const int bid = blockIdx.y * gridDim.x + blockIdx.x;
    const int swz = (bid & 7) * (nwg >> 3) + (bid >> 3);   // bijective, nwg % 8 == 0
    const int m0 = (swz % gridDim.x) * 256;
    const int yy = swz / gridDim.x;
    int n0, kch;
    if constexpr (MODE == 2) {
        kch = yy >> 2;            // 4 K-chunks
        n0 = (yy & 3) * 256;      // N/256 = 4
    } else {
        kch = 0;
        n0 = yy * 256;
    }
    const size_t kbase = (size_t)kch * K;
    const size_t aoff = (size_t)m0 * LDA + kbase + sc * 8;
    const size_t boff = (size_t)n0 * LDA + kbase + sc * 8;

    const f32x4 zero4 = {0.f, 0.f, 0.f, 0.f};
    f32x4 acc[MFR][NFR];
#pragma unroll
    for (int i = 0; i < MFR; i++)
#pragma unroll
        for (int j = 0; j < NFR; j++) acc[i][j] = zero4;

    auto stage = [&](int bb, int t1) {
#pragma unroll
        for (int j = 0; j < 4; j++) {
            int rbase = j * 64 + wv * 8;
            gload16(A  + aoff + (size_t)(rbase + lr) * LDA + (size_t)t1 * 64, &As[bb][rbase * 64]);
            gload16(Bt + boff + (size_t)(rbase + lr) * LDA + (size_t)t1 * 64, &Bs[bb][rbase * 64]);
        }
    };

    stage(0, 0);
    __syncthreads();   // implicit vmcnt(0): tile 0 landed

    const int NT = K >> 6;
    int cur = 0;
    for (int t = 0; t < NT; ++t) {
        if (t + 1 < NT) stage(cur ^ 1, t + 1);   // issue BEFORE compute — hides under MFMA
        const char* Ac = (const char*)&As[cur][0];
        const char* Bc = (const char*)&Bs[cur][0];
#pragma unroll
        for (int kk = 0; kk < 2; kk++) {
            s16x8 aF[MFR], bF[NFR];
#pragma unroll
            for (int mf = 0; mf < MFR; mf++) {
                int row = wm * 128 + mf * 16 + r4;
                aF[mf] = *(const s16x8*)(Ac + ((row * 128 + kk * 64 + g * 16) ^ ((row & 7) << 4)));
            }
#pragma unroll
            for (int nf = 0; nf < NFR; nf++) {
                int row = wn * 64 + nf * 16 + r4;
                bF[nf] = *(const s16x8*)(Bc + ((row * 128 + kk * 64 + g * 16) ^ ((row & 7) << 4)));
            }
#pragma unroll
            for (int mf = 0; mf < MFR; mf++)
#pragma unroll
                for (int nf = 0; nf < NFR; nf++)
                    acc[mf][nf] = __builtin_amdgcn_mfma_f32_16x16x32_bf16(
                        aF[mf], bF[nf], acc[mf][nf], 0, 0, 0);
        }
        __syncthreads();   // ONE barrier/K-tile: drains vmcnt (tile t+1 visible) + frees buf[cur]
        cur ^= 1;
    }

    // epilogue: D layout col = lane&15, row = 4*(lane>>4)+r  [verified m89/m91]
#pragma unroll
    for (int mf = 0; mf < MFR; mf++) {
#pragma unroll
        for (int nf = 0; nf < NFR; nf++) {
            int n = n0 + wn * 64 + nf * 16 + r4;
            int mB = m0 + wm * 128 + mf * 16 + 4 * g;   // base m for r=0 (4 consecutive)
            if constexpr (MODE == 0) {
                int sel = n >> 10, nn = n & 1023;
                const float* bp = (sel == 0) ? b0 : ((sel == 1) ? b1 : b2);
                float bias = bp[nn];
                int h = nn >> 6, d = nn & 63;
                int bb2 = mB >> 11, tt = mB & 2047;
                size_t qz = ((size_t)(bb2 * HEADS + h) * T_SEQ + tt) * HD + d;
                if (sel == 0) {
                    // q consumed only by attn: pre-scale by 0.125*log2(e) (exp2-domain softmax)
#pragma unroll
                    for (int r = 0; r < 4; r++)
                        os0[qz + (size_t)r * HD] = f2bf((acc[mf][nf][r] + bias) * 0.18033688f);
                } else if (sel == 1) {
#pragma unroll
                    for (int r = 0; r < 4; r++) {
                        float val = acc[mf][nf][r] + bias;
                        os1[qz + (size_t)r * HD] = f2bf(val);
                        of0[qz + (size_t)r * HD] = val;            // kout
                    }
                } else {
                    s16x4 vp;
#pragma unroll
                    for (int r = 0; r < 4; r++) {
                        float val = acc[mf][nf][r] + bias;
                        of0[4194304 + qz + (size_t)r * HD] = val;  // vout
                        vp[r] = f2bf(val);
                    }
                    *(s16x4*)&os2[((size_t)(bb2 * HEADS + h) * HD + d) * T_SEQ + tt] = vp;
                }
            } else if constexpr (MODE == 1) {
                float bias = b0[n];
#pragma unroll
                for (int r = 0; r < 4; r++) {
                    float val = acc[mf][nf][r] + bias;
                    // tanh-form GELU: val * e/(e+1), e = exp2(2*log2e*0.79788456*(v+0.044715 v^3))
                    float u = val * (0.7978845608f + 0.0356774081f * val * val);
                    float e = exp2f(fminf(u * 2.885390082f, 126.f));
                    val = val * (e / (e + 1.f));
                    os0[(size_t)(mB + r) * N + n] = f2bf(val);
                }
            } else {
#pragma unroll
                for (int r = 0; r < 4; r++)
                    os0[(size_t)kch * 4194304 + (size_t)(mB + r) * N + n] = f2bf(acc[mf][nf][r]);
            }
        }
    }
}

// ---------------- causal flash attention — R18: 8 waves, kv-parity groups, XCD banding -------
// 256 blocks, 512 threads. XCD remap: linear = by*8+bx; xcd = linear&7; slot = linear>>3;
// bh = xcd*4 + (slot&3); bx = slot>>2 (bijective; K/V band 2MB per XCD L2 — FETCH 74->12MB).
// Wave w: q sub-tile wq = w&3 (32 q rows), kv-parity group g2 = w>>2 (tiles st = 2i+g2).
// Balanced pairing over 128-row q-tiles: phases qtr = {15-bx, bx}. K/V double-buffered per
// group; K/V frag reads SHARED across the wave's two qh-sets. End of phase: group merge via
// LDS overlays. Mask -3e38 (exp2(p-mrun)=0 even while mrun=-1e30). setprio kept (m191: attn +).
__global__ __launch_bounds__(512) void attn_kernel(
    const short* __restrict__ qb, const short* __restrict__ kb,
    const short* __restrict__ vtb, float* __restrict__ y) {
    __shared__ short Ks[2][2][64 * 64];   // [group][buf]
    __shared__ short Vs[2][2][64 * 64];
    __shared__ short Ps[8][32 * 64];      // per-wave P tiles; overlaid as Ymrg during merge
    __shared__ float MLb[4][2][16][2];    // [wq][qh][r4][{m,l}] from group 1
    float* Ymrg = (float*)&Ps[0][0];      // [wq][32 rows][64 cols] fp32 = 8KB per wq

    int linear = blockIdx.y * gridDim.x + blockIdx.x;
    int xcd = linear & 7, slot = linear >> 3;
    int bh = xcd * 4 + (slot & 3);        // head band per XCD
    int bx = slot >> 2;                   // 0..7 within band
    int tid = threadIdx.x, w = tid >> 6, lane = tid & 63, g = lane >> 4, r4 = lane & 15;
    int wq = w & 3, g2 = w >> 2;
    int lr = lane >> 3, lc = lane & 7, sc = lc ^ lr;
    const f32x4 zero4 = {0.f, 0.f, 0.f, 0.f};

    for (int ph = 0; ph < 2; ++ph) {
        int qtr = ph ? bx : (15 - bx);
        int qbase = qtr * 128;

        const short* Qp = qb + ((size_t)bh * T_SEQ + qbase + wq * 32 + r4) * HD;
        s16x8 qf[2][2];
        qf[0][0] = *(const s16x8*)&Qp[g * 8];
        qf[0][1] = *(const s16x8*)&Qp[32 + g * 8];
        qf[1][0] = *(const s16x8*)&Qp[16 * HD + g * 8];
        qf[1][1] = *(const s16x8*)&Qp[16 * HD + 32 + g * 8];

        f32x4 yacc[2][4];
#pragma unroll
        for (int qh = 0; qh < 2; qh++)
#pragma unroll
            for (int ni = 0; ni < 4; ni++) yacc[qh][ni] = zero4;
        float mrun[2] = {-1e30f, -1e30f}, lrun[2] = {0.f, 0.f};

        // stage group tile i=0 (kv base g2*64) into buf 0
#pragma unroll
        for (int j = 0; j < 2; j++) {
            int rw = (wq * 2 + j) * 8 + lr;
            gload16(kb  + ((size_t)bh * T_SEQ + g2 * 64 + rw) * HD + sc * 8,
                    &Ks[g2][0][(wq * 2 + j) * 512]);
            gload16(vtb + ((size_t)bh * HD + rw) * T_SEQ + g2 * 64 + sc * 8,
                    &Vs[g2][0][(wq * 2 + j) * 512]);
        }
        VMCNT0;
        __syncthreads();

        for (int i = 0; i <= qtr; ++i) {
            int cur = i & 1;
            int s0 = (2 * i + g2) * 64;
            if (i + 1 <= qtr) {   // prefetch group's next tile (kv s0+128) into other buffer
#pragma unroll
                for (int j = 0; j < 2; j++) {
                    int rw = (wq * 2 + j) * 8 + lr;
                    gload16(kb  + ((size_t)bh * T_SEQ + s0 + 128 + rw) * HD + sc * 8,
                            &Ks[g2][cur ^ 1][(wq * 2 + j) * 512]);
                    gload16(vtb + ((size_t)bh * HD + rw) * T_SEQ + s0 + 128 + sc * 8,
                            &Vs[g2][cur ^ 1][(wq * 2 + j) * 512]);
                }
            }
            // ---- S^T = K Q^T for both qh sets; kf read ONCE per (kk,sb)
            f32x4 sacc[2][4];
#pragma unroll
            for (int qh = 0; qh < 2; qh++)
#pragma unroll
                for (int sb = 0; sb < 4; sb++) sacc[qh][sb] = zero4;
            PRIO1;
#pragma unroll
            for (int kk = 0; kk < 2; kk++) {
#pragma unroll
                for (int sb = 0; sb < 4; sb++) {
                    int srow = sb * 16 + r4;
                    s16x8 kf = *(const s16x8*)((const char*)&Ks[g2][cur][0] +
                                ((srow * 128 + kk * 64 + g * 16) ^ ((r4 & 7) << 4)));
                    sacc[0][sb] = __builtin_amdgcn_mfma_f32_16x16x32_bf16(kf, qf[0][kk], sacc[0][sb], 0, 0, 0);
                    sacc[1][sb] = __builtin_amdgcn_mfma_f32_16x16x32_bf16(kf, qf[1][kk], sacc[1][sb], 0, 0, 0);
                }
            }
            PRIO0;
            // ---- online softmax per qh set (lane owns q = qbase + wq*32 + qh*16 + r4)
            bool diag = (i == qtr);
            float p[2][4][4];
#pragma unroll
            for (int qh = 0; qh < 2; qh++) {
                float mx = -3e38f;
#pragma unroll
                for (int sb = 0; sb < 4; sb++)
#pragma unroll
                    for (int r = 0; r < 4; r++) {
                        float v = sacc[qh][sb][r];
                        if (diag) {
                            int kv = s0 + sb * 16 + 4 * g + r;
                            int qg = qbase + wq * 32 + qh * 16 + r4;
                            if (kv > qg) v = -3e38f;
                        }
                        p[qh][sb][r] = v;
                        mx = fmaxf(mx, v);
                    }
                mx = fmaxf(mx, __shfl_xor(mx, 16, 64));
                mx = fmaxf(mx, __shfl_xor(mx, 32, 64));
                if (!__all(mx <= mrun[qh] + 8.f)) {
                    float mnew = fmaxf(mrun[qh], mx);
                    float alpha = exp2f(mrun[qh] - mnew);
                    float aC[4];
#pragma unroll
                    for (int r = 0; r < 4; r++) aC[r] = __shfl(alpha, 4 * g + r, 64);
#pragma unroll
                    for (int ni = 0; ni < 4; ni++)
#pragma unroll
                        for (int r = 0; r < 4; r++) yacc[qh][ni][r] *= aC[r];
                    lrun[qh] *= alpha;
                    mrun[qh] = mnew;
                }
                float rsum = 0.f;
#pragma unroll
                for (int sb = 0; sb < 4; sb++)
#pragma unroll
                    for (int r = 0; r < 4; r++) {
                        float e = exp2f(p[qh][sb][r] - mrun[qh]);
                        p[qh][sb][r] = e;
                        rsum += e;
                    }
                rsum += __shfl_xor(rsum, 16, 64);
                rsum += __shfl_xor(rsum, 32, 64);
                lrun[qh] += rsum;
                // P -> per-wave LDS (row = qh*16 + r4; row&7 == r4&7)
#pragma unroll
                for (int sb = 0; sb < 4; sb++) {
                    s16x4 pk;
#pragma unroll
                    for (int r = 0; r < 4; r++) pk[r] = f2bf(p[qh][sb][r]);
                    int off = (((qh * 16 + r4) * 128) + (sb * 16 + 4 * g) * 2) ^ ((r4 & 7) << 4);
                    *(s16x4*)((char*)&Ps[w][0] + off) = pk;
                }
            }
            // ---- Y += P V for both qh sets; vb read ONCE per (kk,ni)
            PRIO1;
#pragma unroll
            for (int kk = 0; kk < 2; kk++) {
                s16x8 pf[2];
#pragma unroll
                for (int qh = 0; qh < 2; qh++)
                    pf[qh] = *(const s16x8*)((const char*)&Ps[w][0] +
                              ((((qh * 16 + r4) * 128) + kk * 64 + g * 16) ^ ((r4 & 7) << 4)));
#pragma unroll
                for (int ni = 0; ni < 4; ni++) {
                    int vrow = ni * 16 + r4;
                    s16x8 vb = *(const s16x8*)((const char*)&Vs[g2][cur][0] +
                                ((vrow * 128 + kk * 64 + g * 16) ^ ((r4 & 7) << 4)));
                    yacc[0][ni] = __builtin_amdgcn_mfma_f32_16x16x32_bf16(pf[0], vb, yacc[0][ni], 0, 0, 0);
                    yacc[1][ni] = __builtin_amdgcn_mfma_f32_16x16x32_bf16(pf[1], vb, yacc[1][ni], 0, 0, 0);
                }
            }
            PRIO0;
            VMCNT0;          // own staging landed
            __syncthreads(); // lockstep step boundary (both groups)
        }
        // ---- cross-group merge: group 1 publishes (m, l, yacc) via LDS
        if (g2 == 1) {
            if (g == 0) {
#pragma unroll
                for (int qh = 0; qh < 2; qh++) {
                    MLb[wq][qh][r4][0] = mrun[qh];
                    MLb[wq][qh][r4][1] = lrun[qh];
                }
            }
#pragma unroll
            for (int qh = 0; qh < 2; qh++)
#pragma unroll
                for (int ni = 0; ni < 4; ni++)
#pragma unroll
                    for (int r = 0; r < 4; r++)
                        Ymrg[wq * 2048 + (qh * 16 + 4 * g + r) * 64 + ni * 16 + r4] = yacc[qh][ni][r];
        }
        __syncthreads();
        if (g2 == 0) {
            int bb = bh >> 4, h = bh & 15;
#pragma unroll
            for (int qh = 0; qh < 2; qh++) {
                float m_b = MLb[wq][qh][r4][0], l_b = MLb[wq][qh][r4][1];
                float mM = fmaxf(mrun[qh], m_b);
                float fa = exp2f(mrun[qh] - mM), fb = exp2f(m_b - mM);
                float lM = lrun[qh] * fa + l_b * fb;
                float faC[4], fbC[4], lC[4];
#pragma unroll
                for (int r = 0; r < 4; r++) {
                    faC[r] = __shfl(fa, 4 * g + r, 64);
                    fbC[r] = __shfl(fb, 4 * g + r, 64);
                    lC[r]  = __shfl(lM, 4 * g + r, 64);
                }
#pragma unroll
                for (int ni = 0; ni < 4; ni++)
#pragma unroll
                    for (int r = 0; r < 4; r++) {
                        float yv = yacc[qh][ni][r] * faC[r] +
                                   Ymrg[wq * 2048 + (qh * 16 + 4 * g + r) * 64 + ni * 16 + r4] * fbC[r];
                        int q = qbase + wq * 32 + qh * 16 + 4 * g + r;
                        y[((size_t)bb * T_SEQ + q) * C_DIM + h * HD + ni * 16 + r4] = yv / lC[r];
                    }
            }
        }
        __syncthreads();   // merge reads done before next phase restages/rewrites
    }
}

extern "C" void kernel_launch(void* const* d_in, const int* in_sizes, int n_in,
                              void* d_out, int out_size, void* d_ws, size_t ws_size,
                              hipStream_t stream) {
    (void)in_sizes; (void)n_in; (void)out_size; (void)ws_size;
    const float* x    = (const float*)d_in[0];
    const float* wq   = (const float*)d_in[1];
    const float* bq   = (const float*)d_in[2];
    const float* wk   = (const float*)d_in[3];
    const float* bk   = (const float*)d_in[4];
    const float* wvp  = (const float*)d_in[5];
    const float* bv   = (const float*)d_in[6];
    const float* ln1w = (const float*)d_in[7];
    const float* ln1b = (const float*)d_in[8];
    const float* ln2w = (const float*)d_in[9];
    const float* ln2b = (const float*)d_in[10];
    const float* wfc  = (const float*)d_in[11];
    const float* bfc  = (const float*)d_in[12];
    const float* wpr  = (const float*)d_in[13];
    const float* bpr  = (const float*)d_in[14];

    float* xout = (float*)d_out;                 // [2,2048,1024]
    float* kout = xout + 4194304;                // [2,16,2048,64] (vout = kout + 4194304)

    // workspace layout (~124 MB)
    short* wqkvt = (short*)d_ws;                 // [3072][1024] bf16
    short* wfct  = wqkvt + 3072 * 1024;          // [4096][1024]
    short* wprt  = wfct + 4096 * 1024;           // [1024][4096]
    short* hb    = wprt + 1024 * 4096;           // LN1 out bf16 [4096][1024]
    short* qb    = hb + 4096 * 1024;             // Q bf16 [B,H,T,D] (pre-scaled)
    short* kbuf  = qb + 4096 * 1024;             // K bf16 [B,H,T,D]
    short* vtb   = kbuf + 4096 * 1024;           // V bf16 transposed [B,H,D,T]
    short* h2b   = vtb + 4096 * 1024;            // LN2 out bf16
    short* fcb   = h2b + 4096 * 1024;            // gelu(fc) bf16 [4096][4096]
    float* ybuf  = (float*)(fcb + 4096 * 4096);  // attn out fp32 [4096][1024]
    short* pbuf  = qb;                           // PROJ partials: 4 x 8MB bf16 (qb..h2b dead)

    // fused transposes + LN1
    prep_kernel<<<15360, 256, 0, stream>>>(wq, wk, wvp, wfc, wpr,
        wqkvt, wfct, wprt, x, ln1w, ln1b, hb);

    // fused QKV GEMM: M=4096, N=3072, K=1024 — 256² 2-phase, grid 16x12 = 192
    gemm2p<0><<<dim3(16, 12), 512, 0, stream>>>(hb, wqkvt, 1024, 1024, 3072,
        bq, bk, bv, qb, kbuf, vtb, kout);

    // attention: 256 blocks x 8 waves (R18 structure) + XCD head-banding remap
    attn_kernel<<<dim3(8, 32), 512, 0, stream>>>(qb, kbuf, vtb, ybuf);

    // x+y residual, LN2, and xout init (= x+y+b_proj)
    resln_kernel<<<4096, 256, 0, stream>>>(x, ybuf, ln2w, ln2b, bpr, h2b, xout);

    // MLP fc + gelu: M=4096, N=4096, K=1024 — 256² 2-phase, grid 16x16 = 256
    gemm2p<1><<<dim3(16, 16), 512, 0, stream>>>(h2b, wfct, 1024, 1024, 4096,
        bfc, nullptr, nullptr, fcb, nullptr, nullptr, nullptr);

    // MLP proj, split-K=4 (K-chunks of 1024), bf16 partials — 256² 2-phase, grid 16x16 = 256
    gemm2p<2><<<dim3(16, 16), 512, 0, stream>>>(fcb, wprt, 1024, 4096, 1024,
        nullptr, nullptr, nullptr, pbuf, nullptr, nullptr, nullptr);

    // xout += sum of partials
    reduce_kernel<<<4096, 256, 0, stream>>>(pbuf, xout);
}

// Round 23
// 216.764 us; speedup vs baseline: 1.2435x; 1.0099x over previous
//
#include <hip/hip_runtime.h>
#include <hip/hip_bf16.h>

// Transformer block fwd: B=2, T=2048, C=1024, H=16, D=64.
// out = concat(x_out fp32 [2,2048,1024], k fp32 [2,16,2048,64], v fp32 [2,16,2048,64])
// R23 = R22 (218.9 us) with setprio ALSO stripped from lockstep attn (same mechanism as
// the GEMM win: setprio pair perturbs scheduling in barrier-lockstep kernels, m190).

#define T_SEQ 2048
#define C_DIM 1024
#define HEADS 16
#define HD    64

typedef __attribute__((ext_vector_type(8))) short s16x8;   // 8 x bf16 (4 VGPR) — MFMA A/B frag
typedef __attribute__((ext_vector_type(4))) short s16x4;
typedef __attribute__((ext_vector_type(4))) float f32x4;   // MFMA C/D frag

__device__ __forceinline__ short f2bf(float f) {
    union { __hip_bfloat16 h; short s; } u;
    u.h = __float2bfloat16(f);
    return u.s;
}
__device__ __forceinline__ float bf2f(short s) {
    union { float f; unsigned u; } u;
    u.u = ((unsigned)(unsigned short)s) << 16;
    return u.f;
}

// async global->LDS, 16B per lane. LDS dest = wave-uniform base + lane*16 (linear).
__device__ __forceinline__ void gload16(const void* g, void* l) {
    __builtin_amdgcn_global_load_lds(
        (const __attribute__((address_space(1))) void*)g,
        (__attribute__((address_space(3))) void*)l, 16, 0, 0);
}
#define VMCNT0 asm volatile("s_waitcnt vmcnt(0)" ::: "memory")

// ---------------- fused prep: 5 weight transposes (fp32 -> bf16, [K][N] -> [N][K]) + LN1 ----
__global__ __launch_bounds__(256) void prep_kernel(
    const float* __restrict__ wq, const float* __restrict__ wk, const float* __restrict__ wv,
    const float* __restrict__ wfc, const float* __restrict__ wpr,
    short* __restrict__ wqkvt, short* __restrict__ wfct, short* __restrict__ wprt,
    const float* __restrict__ x, const float* __restrict__ ln1w, const float* __restrict__ ln1b,
    short* __restrict__ hb) {
    int b = blockIdx.x, tid = threadIdx.x;
    if (b < 11264) {
        const float* W; short* Wt; int K, N, n0, k0;
        if (b < 3072) {
            int which = b >> 10, sub = b & 1023;
            W = (which == 0) ? wq : ((which == 1) ? wk : wv);
            Wt = wqkvt + which * 1024 * 1024;
            K = 1024; N = 1024;
            n0 = (sub & 31) * 32; k0 = (sub >> 5) * 32;
        } else if (b < 7168) {
            int sub = b - 3072;
            W = wfc; Wt = wfct; K = 1024; N = 4096;
            n0 = (sub & 127) * 32; k0 = (sub >> 7) * 32;
        } else {
            int sub = b - 7168;
            W = wpr; Wt = wprt; K = 4096; N = 1024;
            n0 = (sub & 31) * 32; k0 = (sub >> 5) * 32;
        }
        __shared__ float t[32][33];
        int ty = tid >> 3, tx = tid & 7;
        float4 v = *(const float4*)&W[(size_t)(k0 + ty) * N + n0 + tx * 4];
        t[ty][tx * 4 + 0] = v.x; t[ty][tx * 4 + 1] = v.y;
        t[ty][tx * 4 + 2] = v.z; t[ty][tx * 4 + 3] = v.w;
        __syncthreads();
        int r = tid >> 3, c = tid & 7;
        s16x4 o;
#pragma unroll
        for (int j = 0; j < 4; j++) o[j] = f2bf(t[c * 4 + j][r]);
        *(s16x4*)&Wt[(size_t)(n0 + r) * K + k0 + c * 4] = o;
    } else {
        int row = b - 11264;
        float4 v = ((const float4*)(x + (size_t)row * C_DIM))[tid];
        float s  = v.x + v.y + v.z + v.w;
        float sq = v.x * v.x + v.y * v.y + v.z * v.z + v.w * v.w;
#pragma unroll
        for (int off = 32; off > 0; off >>= 1) {
            s  += __shfl_down(s, off, 64);
            sq += __shfl_down(sq, off, 64);
        }
        __shared__ float rs[4], rq[4];
        int wv2 = tid >> 6, ln = tid & 63;
        if (ln == 0) { rs[wv2] = s; rq[wv2] = sq; }
        __syncthreads();
        s = rs[0] + rs[1] + rs[2] + rs[3];
        sq = rq[0] + rq[1] + rq[2] + rq[3];
        float mean = s * (1.f / C_DIM);
        float rstd = rsqrtf(sq * (1.f / C_DIM) - mean * mean + 1e-5f);
        float4 wv4 = ((const float4*)ln1w)[tid];
        float4 bv4 = ((const float4*)ln1b)[tid];
        s16x4 o;
        o[0] = f2bf((v.x - mean) * rstd * wv4.x + bv4.x);
        o[1] = f2bf((v.y - mean) * rstd * wv4.y + bv4.y);
        o[2] = f2bf((v.z - mean) * rstd * wv4.z + bv4.z);
        o[3] = f2bf((v.w - mean) * rstd * wv4.w + bv4.w);
        *(s16x4*)(hb + (size_t)row * C_DIM + tid * 4) = o;
    }
}

// ---- residual + LN2 + PROJ-output init: xout = x+y+b_proj (fp32), h2 = LN(x+y) bf16 ----
__global__ __launch_bounds__(256) void resln_kernel(
    const float* __restrict__ x, const float* __restrict__ y,
    const float* __restrict__ w, const float* __restrict__ b,
    const float* __restrict__ bproj,
    short* __restrict__ out, float* __restrict__ xout) {
    int row = blockIdx.x, tid = threadIdx.x;
    float4 vx = ((const float4*)(x + row * C_DIM))[tid];
    float4 vy = ((const float4*)(y + row * C_DIM))[tid];
    float4 v;
    v.x = vx.x + vy.x; v.y = vx.y + vy.y; v.z = vx.z + vy.z; v.w = vx.w + vy.w;
    float4 bp = ((const float4*)bproj)[tid];
    float4 xo;
    xo.x = v.x + bp.x; xo.y = v.y + bp.y; xo.z = v.z + bp.z; xo.w = v.w + bp.w;
    ((float4*)(xout + row * C_DIM))[tid] = xo;   // reduce_kernel adds PROJ partials onto this
    float s  = v.x + v.y + v.z + v.w;
    float sq = v.x * v.x + v.y * v.y + v.z * v.z + v.w * v.w;
#pragma unroll
    for (int off = 32; off > 0; off >>= 1) {
        s  += __shfl_down(s, off, 64);
        sq += __shfl_down(sq, off, 64);
    }
    __shared__ float rs[4], rq[4];
    int wv = tid >> 6, ln = tid & 63;
    if (ln == 0) { rs[wv] = s; rq[wv] = sq; }
    __syncthreads();
    s = rs[0] + rs[1] + rs[2] + rs[3];
    sq = rq[0] + rq[1] + rq[2] + rq[3];
    float mean = s * (1.f / C_DIM);
    float rstd = rsqrtf(sq * (1.f / C_DIM) - mean * mean + 1e-5f);
    float4 wv4 = ((const float4*)w)[tid];
    float4 bv4 = ((const float4*)b)[tid];
    s16x4 o;
    o[0] = f2bf((v.x - mean) * rstd * wv4.x + bv4.x);
    o[1] = f2bf((v.y - mean) * rstd * wv4.y + bv4.y);
    o[2] = f2bf((v.z - mean) * rstd * wv4.z + bv4.z);
    o[3] = f2bf((v.w - mean) * rstd * wv4.w + bv4.w);
    *(s16x4*)(out + row * C_DIM + tid * 4) = o;
}

// ---- split-K reduce: xout += sum of 4 bf16 partials (xout pre-init = x+y+b_proj) ----
__global__ __launch_bounds__(256) void reduce_kernel(
    const short* __restrict__ p, float* __restrict__ xout) {
    size_t i = (size_t)blockIdx.x * 256 + threadIdx.x;   // float4 index
    float4 a = ((const float4*)xout)[i];
#pragma unroll
    for (int c = 0; c < 4; c++) {
        s16x4 v = ((const s16x4*)(p + (size_t)c * 4194304))[i];
        a.x += bf2f(v[0]); a.y += bf2f(v[1]); a.z += bf2f(v[2]); a.w += bf2f(v[3]);
    }
    ((float4*)xout)[i] = a;
}

// ---------------- 256x256 2-phase GEMM (T3 minimum recipe; R13-proven, no setprio) ----------
// MODE 0: fused QKV (q pre-scaled by 0.125*log2e for exp2-domain attn; packed vT);
// MODE 1: FC + tanh-form GELU (one exp2); MODE 2: split-K bf16 partials (no atomics).
template<int MODE>
__global__ __launch_bounds__(512, 1) void gemm2p(
    const short* __restrict__ A, const short* __restrict__ Bt,
    int K, int LDA, int N,
    const float* __restrict__ b0, const float* __restrict__ b1, const float* __restrict__ b2,
    short* __restrict__ os0, short* __restrict__ os1, short* __restrict__ os2,
    float* __restrict__ of0) {
    constexpr int MFR = 8, NFR = 4;                 // wave tile 128x64, 16x16 frags

    __shared__ short As[2][256 * 64];
    __shared__ short Bs[2][256 * 64];

    const int tid = threadIdx.x;
    const int wv = tid >> 6, lane = tid & 63, g = lane >> 4, r4 = lane & 15;
    const int wm = wv >> 2, wn = wv & 3;
    const int lr = lane >> 3, lc = lane & 7, sc = lc ^ lr;

    const int nwg = gridDim.x * gridDim.y;
    const int bid = blockIdx.y * gridDim.x + blockIdx.x;
    const int swz = (bid & 7) * (nwg >> 3) + (bid >> 3);   // bijective, nwg % 8 == 0
    const int m0 = (swz % gridDim.x) * 256;
    const int yy = swz / gridDim.x;
    int n0, kch;
    if constexpr (MODE == 2) {
        kch = yy >> 2;            // 4 K-chunks
        n0 = (yy & 3) * 256;      // N/256 = 4
    } else {
        kch = 0;
        n0 = yy * 256;
    }
    const size_t kbase = (size_t)kch * K;
    const size_t aoff = (size_t)m0 * LDA + kbase + sc * 8;
    const size_t boff = (size_t)n0 * LDA + kbase + sc * 8;

    const f32x4 zero4 = {0.f, 0.f, 0.f, 0.f};
    f32x4 acc[MFR][NFR];
#pragma unroll
    for (int i = 0; i < MFR; i++)
#pragma unroll
        for (int j = 0; j < NFR; j++) acc[i][j] = zero4;

    auto stage = [&](int bb, int t1) {
#pragma unroll
        for (int j = 0; j < 4; j++) {
            int rbase = j * 64 + wv * 8;
            gload16(A  + aoff + (size_t)(rbase + lr) * LDA + (size_t)t1 * 64, &As[bb][rbase * 64]);
            gload16(Bt + boff + (size_t)(rbase + lr) * LDA + (size_t)t1 * 64, &Bs[bb][rbase * 64]);
        }
    };

    stage(0, 0);
    __syncthreads();   // implicit vmcnt(0): tile 0 landed

    const int NT = K >> 6;
    int cur = 0;
    for (int t = 0; t < NT; ++t) {
        if (t + 1 < NT) stage(cur ^ 1, t + 1);   // issue BEFORE compute — hides under MFMA
        const char* Ac = (const char*)&As[cur][0];
        const char* Bc = (const char*)&Bs[cur][0];
#pragma unroll
        for (int kk = 0; kk < 2; kk++) {
            s16x8 aF[MFR], bF[NFR];
#pragma unroll
            for (int mf = 0; mf < MFR; mf++) {
                int row = wm * 128 + mf * 16 + r4;
                aF[mf] = *(const s16x8*)(Ac + ((row * 128 + kk * 64 + g * 16) ^ ((row & 7) << 4)));
            }
#pragma unroll
            for (int nf = 0; nf < NFR; nf++) {
                int row = wn * 64 + nf * 16 + r4;
                bF[nf] = *(const s16x8*)(Bc + ((row * 128 + kk * 64 + g * 16) ^ ((row & 7) << 4)));
            }
#pragma unroll
            for (int mf = 0; mf < MFR; mf++)
#pragma unroll
                for (int nf = 0; nf < NFR; nf++)
                    acc[mf][nf] = __builtin_amdgcn_mfma_f32_16x16x32_bf16(
                        aF[mf], bF[nf], acc[mf][nf], 0, 0, 0);
        }
        __syncthreads();   // ONE barrier/K-tile: drains vmcnt (tile t+1 visible) + frees buf[cur]
        cur ^= 1;
    }

    // epilogue: D layout col = lane&15, row = 4*(lane>>4)+r  [verified m89/m91]
#pragma unroll
    for (int mf = 0; mf < MFR; mf++) {
#pragma unroll
        for (int nf = 0; nf < NFR; nf++) {
            int n = n0 + wn * 64 + nf * 16 + r4;
            int mB = m0 + wm * 128 + mf * 16 + 4 * g;   // base m for r=0 (4 consecutive)
            if constexpr (MODE == 0) {
                int sel = n >> 10, nn = n & 1023;
                const float* bp = (sel == 0) ? b0 : ((sel == 1) ? b1 : b2);
                float bias = bp[nn];
                int h = nn >> 6, d = nn & 63;
                int bb2 = mB >> 11, tt = mB & 2047;
                size_t qz = ((size_t)(bb2 * HEADS + h) * T_SEQ + tt) * HD + d;
                if (sel == 0) {
                    // q consumed only by attn: pre-scale by 0.125*log2(e) (exp2-domain softmax)
#pragma unroll
                    for (int r = 0; r < 4; r++)
                        os0[qz + (size_t)r * HD] = f2bf((acc[mf][nf][r] + bias) * 0.18033688f);
                } else if (sel == 1) {
#pragma unroll
                    for (int r = 0; r < 4; r++) {
                        float val = acc[mf][nf][r] + bias;
                        os1[qz + (size_t)r * HD] = f2bf(val);
                        of0[qz + (size_t)r * HD] = val;            // kout
                    }
                } else {
                    s16x4 vp;
#pragma unroll
                    for (int r = 0; r < 4; r++) {
                        float val = acc[mf][nf][r] + bias;
                        of0[4194304 + qz + (size_t)r * HD] = val;  // vout
                        vp[r] = f2bf(val);
                    }
                    *(s16x4*)&os2[((size_t)(bb2 * HEADS + h) * HD + d) * T_SEQ + tt] = vp;
                }
            } else if constexpr (MODE == 1) {
                float bias = b0[n];
#pragma unroll
                for (int r = 0; r < 4; r++) {
                    float val = acc[mf][nf][r] + bias;
                    // tanh-form GELU: val * e/(e+1), e = exp2(2*log2e*0.79788456*(v+0.044715 v^3))
                    float u = val * (0.7978845608f + 0.0356774081f * val * val);
                    float e = exp2f(fminf(u * 2.885390082f, 126.f));
                    val = val * (e / (e + 1.f));
                    os0[(size_t)(mB + r) * N + n] = f2bf(val);
                }
            } else {
#pragma unroll
                for (int r = 0; r < 4; r++)
                    os0[(size_t)kch * 4194304 + (size_t)(mB + r) * N + n] = f2bf(acc[mf][nf][r]);
            }
        }
    }
}

// ---------------- causal flash attention — R18 structure, no setprio (lockstep regime) -------
// 256 blocks, 512 threads. XCD remap: linear = by*8+bx; xcd = linear&7; slot = linear>>3;
// bh = xcd*4 + (slot&3); bx = slot>>2 (bijective; K/V band 2MB per XCD L2 — FETCH 74->12MB).
// Wave w: q sub-tile wq = w&3 (32 q rows), kv-parity group g2 = w>>2 (tiles st = 2i+g2).
// Balanced pairing over 128-row q-tiles: phases qtr = {15-bx, bx}. K/V double-buffered per
// group; K/V frag reads SHARED across the wave's two qh-sets. End of phase: group merge via
// LDS overlays. Mask -3e38 (exp2(p-mrun)=0 even while mrun=-1e30).
__global__ __launch_bounds__(512) void attn_kernel(
    const short* __restrict__ qb, const short* __restrict__ kb,
    const short* __restrict__ vtb, float* __restrict__ y) {
    __shared__ short Ks[2][2][64 * 64];   // [group][buf]
    __shared__ short Vs[2][2][64 * 64];
    __shared__ short Ps[8][32 * 64];      // per-wave P tiles; overlaid as Ymrg during merge
    __shared__ float MLb[4][2][16][2];    // [wq][qh][r4][{m,l}] from group 1
    float* Ymrg = (float*)&Ps[0][0];      // [wq][32 rows][64 cols] fp32 = 8KB per wq

    int linear = blockIdx.y * gridDim.x + blockIdx.x;
    int xcd = linear & 7, slot = linear >> 3;
    int bh = xcd * 4 + (slot & 3);        // head band per XCD
    int bx = slot >> 2;                   // 0..7 within band
    int tid = threadIdx.x, w = tid >> 6, lane = tid & 63, g = lane >> 4, r4 = lane & 15;
    int wq = w & 3, g2 = w >> 2;
    int lr = lane >> 3, lc = lane & 7, sc = lc ^ lr;
    const f32x4 zero4 = {0.f, 0.f, 0.f, 0.f};

    for (int ph = 0; ph < 2; ++ph) {
        int qtr = ph ? bx : (15 - bx);
        int qbase = qtr * 128;

        const short* Qp = qb + ((size_t)bh * T_SEQ + qbase + wq * 32 + r4) * HD;
        s16x8 qf[2][2];
        qf[0][0] = *(const s16x8*)&Qp[g * 8];
        qf[0][1] = *(const s16x8*)&Qp[32 + g * 8];
        qf[1][0] = *(const s16x8*)&Qp[16 * HD + g * 8];
        qf[1][1] = *(const s16x8*)&Qp[16 * HD + 32 + g * 8];

        f32x4 yacc[2][4];
#pragma unroll
        for (int qh = 0; qh < 2; qh++)
#pragma unroll
            for (int ni = 0; ni < 4; ni++) yacc[qh][ni] = zero4;
        float mrun[2] = {-1e30f, -1e30f}, lrun[2] = {0.f, 0.f};

        // stage group tile i=0 (kv base g2*64) into buf 0
#pragma unroll
        for (int j = 0; j < 2; j++) {
            int rw = (wq * 2 + j) * 8 + lr;
            gload16(kb  + ((size_t)bh * T_SEQ + g2 * 64 + rw) * HD + sc * 8,
                    &Ks[g2][0][(wq * 2 + j) * 512]);
            gload16(vtb + ((size_t)bh * HD + rw) * T_SEQ + g2 * 64 + sc * 8,
                    &Vs[g2][0][(wq * 2 + j) * 512]);
        }
        VMCNT0;
        __syncthreads();

        for (int i = 0; i <= qtr; ++i) {
            int cur = i & 1;
            int s0 = (2 * i + g2) * 64;
            if (i + 1 <= qtr) {   // prefetch group's next tile (kv s0+128) into other buffer
#pragma unroll
                for (int j = 0; j < 2; j++) {
                    int rw = (wq * 2 + j) * 8 + lr;
                    gload16(kb  + ((size_t)bh * T_SEQ + s0 + 128 + rw) * HD + sc * 8,
                            &Ks[g2][cur ^ 1][(wq * 2 + j) * 512]);
                    gload16(vtb + ((size_t)bh * HD + rw) * T_SEQ + s0 + 128 + sc * 8,
                            &Vs[g2][cur ^ 1][(wq * 2 + j) * 512]);
                }
            }
            // ---- S^T = K Q^T for both qh sets; kf read ONCE per (kk,sb)
            f32x4 sacc[2][4];
#pragma unroll
            for (int qh = 0; qh < 2; qh++)
#pragma unroll
                for (int sb = 0; sb < 4; sb++) sacc[qh][sb] = zero4;
#pragma unroll
            for (int kk = 0; kk < 2; kk++) {
#pragma unroll
                for (int sb = 0; sb < 4; sb++) {
                    int srow = sb * 16 + r4;
                    s16x8 kf = *(const s16x8*)((const char*)&Ks[g2][cur][0] +
                                ((srow * 128 + kk * 64 + g * 16) ^ ((r4 & 7) << 4)));
                    sacc[0][sb] = __builtin_amdgcn_mfma_f32_16x16x32_bf16(kf, qf[0][kk], sacc[0][sb], 0, 0, 0);
                    sacc[1][sb] = __builtin_amdgcn_mfma_f32_16x16x32_bf16(kf, qf[1][kk], sacc[1][sb], 0, 0, 0);
                }
            }
            // ---- online softmax per qh set (lane owns q = qbase + wq*32 + qh*16 + r4)
            bool diag = (i == qtr);
            float p[2][4][4];
#pragma unroll
            for (int qh = 0; qh < 2; qh++) {
                float mx = -3e38f;
#pragma unroll
                for (int sb = 0; sb < 4; sb++)
#pragma unroll
                    for (int r = 0; r < 4; r++) {
                        float v = sacc[qh][sb][r];
                        if (diag) {
                            int kv = s0 + sb * 16 + 4 * g + r;
                            int qg = qbase + wq * 32 + qh * 16 + r4;
                            if (kv > qg) v = -3e38f;
                        }
                        p[qh][sb][r] = v;
                        mx = fmaxf(mx, v);
                    }
                mx = fmaxf(mx, __shfl_xor(mx, 16, 64));
                mx = fmaxf(mx, __shfl_xor(mx, 32, 64));
                if (!__all(mx <= mrun[qh] + 8.f)) {
                    float mnew = fmaxf(mrun[qh], mx);
                    float alpha = exp2f(mrun[qh] - mnew);
                    float aC[4];
#pragma unroll
                    for (int r = 0; r < 4; r++) aC[r] = __shfl(alpha, 4 * g + r, 64);
#pragma unroll
                    for (int ni = 0; ni < 4; ni++)
#pragma unroll
                        for (int r = 0; r < 4; r++) yacc[qh][ni][r] *= aC[r];
                    lrun[qh] *= alpha;
                    mrun[qh] = mnew;
                }
                float rsum = 0.f;
#pragma unroll
                for (int sb = 0; sb < 4; sb++)
#pragma unroll
                    for (int r = 0; r < 4; r++) {
                        float e = exp2f(p[qh][sb][r] - mrun[qh]);
                        p[qh][sb][r] = e;
                        rsum += e;
                    }
                rsum += __shfl_xor(rsum, 16, 64);
                rsum += __shfl_xor(rsum, 32, 64);
                lrun[qh] += rsum;
                // P -> per-wave LDS (row = qh*16 + r4; row&7 == r4&7)
#pragma unroll
                for (int sb = 0; sb < 4; sb++) {
                    s16x4 pk;
#pragma unroll
                    for (int r = 0; r < 4; r++) pk[r] = f2bf(p[qh][sb][r]);
                    int off = (((qh * 16 + r4) * 128) + (sb * 16 + 4 * g) * 2) ^ ((r4 & 7) << 4);
                    *(s16x4*)((char*)&Ps[w][0] + off) = pk;
                }
            }
            // ---- Y += P V for both qh sets; vb read ONCE per (kk,ni)
#pragma unroll
            for (int kk = 0; kk < 2; kk++) {
                s16x8 pf[2];
#pragma unroll
                for (int qh = 0; qh < 2; qh++)
                    pf[qh] = *(const s16x8*)((const char*)&Ps[w][0] +
                              ((((qh * 16 + r4) * 128) + kk * 64 + g * 16) ^ ((r4 & 7) << 4)));
#pragma unroll
                for (int ni = 0; ni < 4; ni++) {
                    int vrow = ni * 16 + r4;
                    s16x8 vb = *(const s16x8*)((const char*)&Vs[g2][cur][0] +
                                ((vrow * 128 + kk * 64 + g * 16) ^ ((r4 & 7) << 4)));
                    yacc[0][ni] = __builtin_amdgcn_mfma_f32_16x16x32_bf16(pf[0], vb, yacc[0][ni], 0, 0, 0);
                    yacc[1][ni] = __builtin_amdgcn_mfma_f32_16x16x32_bf16(pf[1], vb, yacc[1][ni], 0, 0, 0);
                }
            }
            VMCNT0;          // own staging landed
            __syncthreads(); // lockstep step boundary (both groups)
        }
        // ---- cross-group merge: group 1 publishes (m, l, yacc) via LDS
        if (g2 == 1) {
            if (g == 0) {
#pragma unroll
                for (int qh = 0; qh < 2; qh++) {
                    MLb[wq][qh][r4][0] = mrun[qh];
                    MLb[wq][qh][r4][1] = lrun[qh];
                }
            }
#pragma unroll
            for (int qh = 0; qh < 2; qh++)
#pragma unroll
                for (int ni = 0; ni < 4; ni++)
#pragma unroll
                    for (int r = 0; r < 4; r++)
                        Ymrg[wq * 2048 + (qh * 16 + 4 * g + r) * 64 + ni * 16 + r4] = yacc[qh][ni][r];
        }
        __syncthreads();
        if (g2 == 0) {
            int bb = bh >> 4, h = bh & 15;
#pragma unroll
            for (int qh = 0; qh < 2; qh++) {
                float m_b = MLb[wq][qh][r4][0], l_b = MLb[wq][qh][r4][1];
                float mM = fmaxf(mrun[qh], m_b);
                float fa = exp2f(mrun[qh] - mM), fb = exp2f(m_b - mM);
                float lM = lrun[qh] * fa + l_b * fb;
                float faC[4], fbC[4], lC[4];
#pragma unroll
                for (int r = 0; r < 4; r++) {
                    faC[r] = __shfl(fa, 4 * g + r, 64);
                    fbC[r] = __shfl(fb, 4 * g + r, 64);
                    lC[r]  = __shfl(lM, 4 * g + r, 64);
                }
#pragma unroll
                for (int ni = 0; ni < 4; ni++)
#pragma unroll
                    for (int r = 0; r < 4; r++) {
                        float yv = yacc[qh][ni][r] * faC[r] +
                                   Ymrg[wq * 2048 + (qh * 16 + 4 * g + r) * 64 + ni * 16 + r4] * fbC[r];
                        int q = qbase + wq * 32 + qh * 16 + 4 * g + r;
                        y[((size_t)bb * T_SEQ + q) * C_DIM + h * HD + ni * 16 + r4] = yv / lC[r];
                    }
            }
        }
        __syncthreads();   // merge reads done before next phase restages/rewrites
    }
}

extern "C" void kernel_launch(void* const* d_in, const int* in_sizes, int n_in,
                              void* d_out, int out_size, void* d_ws, size_t ws_size,
                              hipStream_t stream) {
    (void)in_sizes; (void)n_in; (void)out_size; (void)ws_size;
    const float* x    = (const float*)d_in[0];
    const float* wq   = (const float*)d_in[1];
    const float* bq   = (const float*)d_in[2];
    const float* wk   = (const float*)d_in[3];
    const float* bk   = (const float*)d_in[4];
    const float* wvp  = (const float*)d_in[5];
    const float* bv   = (const float*)d_in[6];
    const float* ln1w = (const float*)d_in[7];
    const float* ln1b = (const float*)d_in[8];
    const float* ln2w = (const float*)d_in[9];
    const float* ln2b = (const float*)d_in[10];
    const float* wfc  = (const float*)d_in[11];
    const float* bfc  = (const float*)d_in[12];
    const float* wpr  = (const float*)d_in[13];
    const float* bpr  = (const float*)d_in[14];

    float* xout = (float*)d_out;                 // [2,2048,1024]
    float* kout = xout + 4194304;                // [2,16,2048,64] (vout = kout + 4194304)

    // workspace layout (~124 MB)
    short* wqkvt = (short*)d_ws;                 // [3072][1024] bf16
    short* wfct  = wqkvt + 3072 * 1024;          // [4096][1024]
    short* wprt  = wfct + 4096 * 1024;           // [1024][4096]
    short* hb    = wprt + 1024 * 4096;           // LN1 out bf16 [4096][1024]
    short* qb    = hb + 4096 * 1024;             // Q bf16 [B,H,T,D] (pre-scaled)
    short* kbuf  = qb + 4096 * 1024;             // K bf16 [B,H,T,D]
    short* vtb   = kbuf + 4096 * 1024;           // V bf16 transposed [B,H,D,T]
    short* h2b   = vtb + 4096 * 1024;            // LN2 out bf16
    short* fcb   = h2b + 4096 * 1024;            // gelu(fc) bf16 [4096][4096]
    float* ybuf  = (float*)(fcb + 4096 * 4096);  // attn out fp32 [4096][1024]
    short* pbuf  = qb;                           // PROJ partials: 4 x 8MB bf16 (qb..h2b dead)

    // fused transposes + LN1
    prep_kernel<<<15360, 256, 0, stream>>>(wq, wk, wvp, wfc, wpr,
        wqkvt, wfct, wprt, x, ln1w, ln1b, hb);

    // fused QKV GEMM: M=4096, N=3072, K=1024 — 256² 2-phase, grid 16x12 = 192
    gemm2p<0><<<dim3(16, 12), 512, 0, stream>>>(hb, wqkvt, 1024, 1024, 3072,
        bq, bk, bv, qb, kbuf, vtb, kout);

    // attention: 256 blocks x 8 waves (R18 structure, no setprio) + XCD head-banding remap
    attn_kernel<<<dim3(8, 32), 512, 0, stream>>>(qb, kbuf, vtb, ybuf);

    // x+y residual, LN2, and xout init (= x+y+b_proj)
    resln_kernel<<<4096, 256, 0, stream>>>(x, ybuf, ln2w, ln2b, bpr, h2b, xout);

    // MLP fc + gelu: M=4096, N=4096, K=1024 — 256² 2-phase, grid 16x16 = 256
    gemm2p<1><<<dim3(16, 16), 512, 0, stream>>>(h2b, wfct, 1024, 1024, 4096,
        bfc, nullptr, nullptr, fcb, nullptr, nullptr, nullptr);

    // MLP proj, split-K=4 (K-chunks of 1024), bf16 partials — 256² 2-phase, grid 16x16 = 256
    gemm2p<2><<<dim3(16, 16), 512, 0, stream>>>(fcb, wprt, 1024, 4096, 1024,
        nullptr, nullptr, nullptr, pbuf, nullptr, nullptr, nullptr);

    // xout += sum of partials
    reduce_kernel<<<4096, 256, 0, stream>>>(pbuf, xout);
}